// Round 1
// 461.308 us; speedup vs baseline: 1.0065x; 1.0065x over previous
//
#include <hip/hip_runtime.h>
#include <math.h>

#define B_ 16
#define L_ 1024
#define H_ 8
#define U_ 35

typedef float f32x4 __attribute__((ext_vector_type(4)));
typedef short bf16x8 __attribute__((ext_vector_type(8)));

__device__ __forceinline__ unsigned short f2bf(float x) {
    unsigned int u = __float_as_uint(x);
    u += 0x7FFFu + ((u >> 16) & 1u);      // round-to-nearest-even
    return (unsigned short)(u >> 16);
}
__device__ __forceinline__ float bf2f(unsigned short b) {
    return __uint_as_float(((unsigned int)b) << 16);
}

#define MFMA(a, b, c) __builtin_amdgcn_mfma_f32_16x16x32_bf16((a), (b), (c), 0, 0, 0)

// ---------------- workspace layout (float-element offsets) ----------------
#define OFF_V      ((size_t)0)           // 8388608 f
#define OFF_QHI    ((size_t)8388608)     // 4194304
#define OFF_QLO    ((size_t)12582912)    // 4194304
#define OFF_CTXP   OFF_QHI               // ctx partials alias q_hi (dead after scores)
#define OFF_KHI    ((size_t)16777216)    // 4194304
#define OFF_KLO    ((size_t)20971520)    // 4194304
#define OFF_S      ((size_t)25165824)    // 4587520
#define OFF_WQH    OFF_S                 // W splits alias S (dead before scores)
#define OFF_WQL    ((size_t)(OFF_S + 131072))
#define OFF_WKH    ((size_t)(OFF_S + 262144))
#define OFF_WKL    ((size_t)(OFF_S + 393216))
#define OFF_WVH    ((size_t)(OFF_S + 524288))
#define OFF_WVL    ((size_t)(OFF_S + 655360))
#define OFF_M      ((size_t)29753344)    // 131072
#define OFF_KMEAN  ((size_t)29884416)    // 8192
#define OFF_VMEAN  ((size_t)29892608)    // 8192
#define OFF_CTXD   ((size_t)29900800)    // 286720 (ctx - vmean diffs)
#define OFF_IDX    ((size_t)30187520)    // 4480
#define OFF_OBASE  ((size_t)30192000)    // 8192 (per-b base output row)
// end ~30.2M f = ~121 MB

// ---------------------------------------------------------------
// split Wq/Wk/Wv fp32 -> hi/lo bf16; grid 3072 x 256
// ---------------------------------------------------------------
__global__ __launch_bounds__(256) void split_w3(
    const float* __restrict__ Wq, const float* __restrict__ Wk,
    const float* __restrict__ Wv,
    unsigned short* __restrict__ wqh, unsigned short* __restrict__ wql,
    unsigned short* __restrict__ wkh, unsigned short* __restrict__ wkl,
    unsigned short* __restrict__ wvh, unsigned short* __restrict__ wvl)
{
    const int w = blockIdx.x >> 10;
    const int i = (blockIdx.x & 1023) * 256 + threadIdx.x;
    const float* W = (w == 0) ? Wq : (w == 1) ? Wk : Wv;
    unsigned short* hi = (w == 0) ? wqh : (w == 1) ? wkh : wvh;
    unsigned short* lo = (w == 0) ? wql : (w == 1) ? wkl : wvl;
    float x = W[i];
    unsigned short h = f2bf(x);
    hi[i] = h;
    lo[i] = f2bf(x - bf2f(h));
}

// ---------------------------------------------------------------
// Fused bf16x2 MFMA GEMM for all three projections.
// blockIdx.z selects {A, W(hi/lo), bias, output}:
//   z=0: q = query@Wq^T+bq  -> q_hi/q_lo bf16 (head layout)
//   z=1: k = key  @Wk^T+bk  -> k_hi/k_lo bf16 (head layout)
//   z=2: v = value@Wv^T+bv  -> fp32          (head layout)
// Grid 128x4x3 = 1536 blocks (was 3 launches of 512 blocks at 2 blocks/CU
// = 21% occupancy, latency-bound: MfmaUtil 11%). Fusing fills the
// LDS-limited 4 blocks/CU and removes two launch gaps.
// ---------------------------------------------------------------
__global__ __launch_bounds__(256) void gemm_qkv(
    const float* __restrict__ Aq, const float* __restrict__ Ak,
    const float* __restrict__ Av,
    const unsigned short* __restrict__ wqh, const unsigned short* __restrict__ wql,
    const unsigned short* __restrict__ wkh, const unsigned short* __restrict__ wkl,
    const unsigned short* __restrict__ wvh, const unsigned short* __restrict__ wvl,
    const float* __restrict__ bqp, const float* __restrict__ bkp,
    const float* __restrict__ bvp,
    float* __restrict__ vout,
    unsigned short* __restrict__ qhi_o, unsigned short* __restrict__ qlo_o,
    unsigned short* __restrict__ khi_o, unsigned short* __restrict__ klo_o)
{
    __shared__ unsigned short Ah[128][40];
    __shared__ unsigned short Al[128][40];
    __shared__ unsigned short Bh[128][40];
    __shared__ unsigned short Bl[128][40];

    const int z = blockIdx.z;
    const float* A = (z == 0) ? Aq : (z == 1) ? Ak : Av;
    const unsigned short* Whi = (z == 0) ? wqh : (z == 1) ? wkh : wvh;
    const unsigned short* Wlo = (z == 0) ? wql : (z == 1) ? wkl : wvl;
    const float* bias = (z == 0) ? bqp : (z == 1) ? bkp : bvp;
    float* outf = (z == 2) ? vout : nullptr;
    unsigned short* ohi = (z == 0) ? qhi_o : (z == 1) ? khi_o : nullptr;
    unsigned short* olo = (z == 0) ? qlo_o : (z == 1) ? klo_o : nullptr;

    const int tid = threadIdx.x, lane = tid & 63, wave = tid >> 6;
    const int m0 = blockIdx.x * 128, n0 = blockIdx.y * 128;
    const int wm = (wave >> 1) * 64, wn = (wave & 1) * 64;

    f32x4 zero4 = {0.f, 0.f, 0.f, 0.f};
    f32x4 acc[4][4];
#pragma unroll
    for (int i = 0; i < 4; i++)
#pragma unroll
        for (int j = 0; j < 4; j++) acc[i][j] = zero4;

    const int ar = tid >> 3, ac = (tid & 7) * 4;
    const int br = tid >> 2, bc = (tid & 3) * 8;
    const int kc = (lane >> 4) * 8;
    const int fr = lane & 15;

    for (int k0 = 0; k0 < 512; k0 += 32) {
        if (k0) __syncthreads();
#pragma unroll
        for (int p = 0; p < 4; ++p) {
            float4 a4 = *(const float4*)(A + (size_t)(m0 + ar + p * 32) * 512 + k0 + ac);
            ushort4 h4, l4;
            h4.x = f2bf(a4.x); l4.x = f2bf(a4.x - bf2f(h4.x));
            h4.y = f2bf(a4.y); l4.y = f2bf(a4.y - bf2f(h4.y));
            h4.z = f2bf(a4.z); l4.z = f2bf(a4.z - bf2f(h4.z));
            h4.w = f2bf(a4.w); l4.w = f2bf(a4.w - bf2f(h4.w));
            *(ushort4*)&Ah[ar + p * 32][ac] = h4;
            *(ushort4*)&Al[ar + p * 32][ac] = l4;
        }
#pragma unroll
        for (int p = 0; p < 2; ++p) {
            size_t off = (size_t)(n0 + br + p * 64) * 512 + k0 + bc;
            *(uint4*)&Bh[br + p * 64][bc] = *(const uint4*)(Whi + off);
            *(uint4*)&Bl[br + p * 64][bc] = *(const uint4*)(Wlo + off);
        }
        __syncthreads();

        bf16x8 ah[4], al[4];
#pragma unroll
        for (int mi = 0; mi < 4; ++mi) {
            int row = wm + mi * 16 + fr;
            ah[mi] = *(bf16x8*)&Ah[row][kc];
            al[mi] = *(bf16x8*)&Al[row][kc];
        }
#pragma unroll
        for (int ni = 0; ni < 4; ++ni) {
            int rn = wn + ni * 16 + fr;
            bf16x8 bh8 = *(bf16x8*)&Bh[rn][kc];
            bf16x8 bl8 = *(bf16x8*)&Bl[rn][kc];
#pragma unroll
            for (int mi = 0; mi < 4; ++mi) {
                acc[mi][ni] = MFMA(ah[mi], bh8, acc[mi][ni]);
                acc[mi][ni] = MFMA(ah[mi], bl8, acc[mi][ni]);
                acc[mi][ni] = MFMA(al[mi], bh8, acc[mi][ni]);
            }
        }
    }

    const int col = lane & 15, rq = (lane >> 4) * 4;
#pragma unroll
    for (int ni = 0; ni < 4; ++ni) {
        int n = n0 + wn + ni * 16 + col;
        float bn = bias[n];
#pragma unroll
        for (int mi = 0; mi < 4; ++mi) {
#pragma unroll
            for (int r = 0; r < 4; ++r) {
                int m = m0 + wm + mi * 16 + rq + r;
                float val = acc[mi][ni][r] + bn;
                size_t off = ((size_t)((m >> 10) * H_ + (n >> 6)) * L_ + (m & 1023)) * 64 + (n & 63);
                if (outf) outf[off] = val;
                if (ohi) {
                    unsigned short h = f2bf(val);
                    ohi[off] = h;
                    olo[off] = f2bf(val - bf2f(h));
                }
            }
        }
    }
}

// ---------------------------------------------------------------
// fused means: blocks 0..127 -> kmean (from k hi/lo), 128..255 -> vmean (fp32)
// ---------------------------------------------------------------
__global__ __launch_bounds__(256) void means_fused(
    const unsigned short* __restrict__ khi, const unsigned short* __restrict__ klo,
    const float* __restrict__ v, float* __restrict__ kmean, float* __restrict__ vmean)
{
    const int which = blockIdx.x >> 7;
    const int bh = blockIdx.x & 127;
    const int d = threadIdx.x & 63, g = threadIdx.x >> 6;
    __shared__ float red[4][64];
    float s = 0.f;
    if (which == 0) {
        size_t base = ((size_t)bh * L_ + g * 256) * 64 + d;
#pragma unroll 8
        for (int l = 0; l < 256; l++) {
            size_t o = base + (size_t)l * 64;
            s += bf2f(khi[o]) + bf2f(klo[o]);
        }
    } else {
        const float* p = v + ((size_t)bh * L_ + g * 256) * 64 + d;
#pragma unroll 8
        for (int l = 0; l < 256; l++) s += p[(size_t)l * 64];
    }
    red[g][d] = s;
    __syncthreads();
    if (threadIdx.x < 64) {
        const int dd = threadIdx.x;
        float m = (red[0][dd] + red[1][dd] + red[2][dd] + red[3][dd]) * (1.0f / 1024.0f);
        (which == 0 ? kmean : vmean)[(size_t)bh * 64 + dd] = m;
    }
}

// ---------------------------------------------------------------
// M[l] = max_k(q_l . k_k) - q_l . kmean via bf16x2 MFMA
// grid (128 bh, 16 qt): XCD-local K reuse (bh%8 pins the XCD).
// Q fragments hoisted to registers (loop-invariant); 64-row K tiles
// (16 kt) cut LDS to ~38 KB for 3-4 blocks/CU occupancy.
// ---------------------------------------------------------------
__global__ __launch_bounds__(256) void qk_rowmax_mfma(
    const unsigned short* __restrict__ qhi, const unsigned short* __restrict__ qlo,
    const unsigned short* __restrict__ khi, const unsigned short* __restrict__ klo,
    const float* __restrict__ kmean, float* __restrict__ Mout)
{
    __shared__ unsigned short Qh[64][72], Ql[64][72];
    __shared__ unsigned short Kh[64][72], Kl[64][72];
    __shared__ float Mred[64][4];
    __shared__ float km[64];
    const int bh = blockIdx.x, q0 = blockIdx.y * 64;
    const int tid = threadIdx.x, lane = tid & 63, wave = tid >> 6;

    if (tid < 64) km[tid] = kmean[bh * 64 + tid];
    {
        int r = tid >> 2, c = (tid & 3) * 16;
        size_t off = ((size_t)bh * L_ + q0 + r) * 64 + c;
        *(uint4*)&Qh[r][c]     = *(const uint4*)(qhi + off);
        *(uint4*)&Qh[r][c + 8] = *(const uint4*)(qhi + off + 8);
        *(uint4*)&Ql[r][c]     = *(const uint4*)(qlo + off);
        *(uint4*)&Ql[r][c + 8] = *(const uint4*)(qlo + off + 8);
    }

    const size_t kb = (size_t)bh * L_ * 64;
    const int sr = tid >> 2, sc = (tid & 3) * 16;
    const int fr = lane & 15;
    f32x4 zero4 = {0.f, 0.f, 0.f, 0.f};

    // register prefetch of K tile 0 (64 rows)
    uint4 pha, phb, pla, plb;
    {
        size_t off = kb + (size_t)sr * 64 + sc;
        pha = *(const uint4*)(khi + off);  phb = *(const uint4*)(khi + off + 8);
        pla = *(const uint4*)(klo + off);  plb = *(const uint4*)(klo + off + 8);
    }

    __syncthreads();   // Q/km staged

    // hoist Q fragments into registers — invariant across the K loop
    bf16x8 qah[2][4], qal[2][4];
#pragma unroll
    for (int ks = 0; ks < 2; ++ks) {
        int kcol = ks * 32 + (lane >> 4) * 8;
#pragma unroll
        for (int mi = 0; mi < 4; ++mi) {
            qah[ks][mi] = *(bf16x8*)&Qh[mi * 16 + fr][kcol];
            qal[ks][mi] = *(bf16x8*)&Ql[mi * 16 + fr][kcol];
        }
    }

    float rmax[4][4];
#pragma unroll
    for (int mi = 0; mi < 4; ++mi)
#pragma unroll
        for (int r = 0; r < 4; ++r) rmax[mi][r] = -INFINITY;

    for (int kt = 0; kt < 16; ++kt) {
        if (kt) __syncthreads();   // previous tile's readers done
        *(uint4*)&Kh[sr][sc] = pha;  *(uint4*)&Kh[sr][sc + 8] = phb;
        *(uint4*)&Kl[sr][sc] = pla;  *(uint4*)&Kl[sr][sc + 8] = plb;
        __syncthreads();

        if (kt < 15) {   // next-tile loads drain behind the MFMAs
            size_t off = kb + (size_t)((kt + 1) * 64 + sr) * 64 + sc;
            pha = *(const uint4*)(khi + off);  phb = *(const uint4*)(khi + off + 8);
            pla = *(const uint4*)(klo + off);  plb = *(const uint4*)(klo + off + 8);
        }

        f32x4 acc[4];
#pragma unroll
        for (int mi = 0; mi < 4; ++mi) acc[mi] = zero4;

#pragma unroll
        for (int ks = 0; ks < 2; ++ks) {
            int kcol = ks * 32 + (lane >> 4) * 8;
            int krow = wave * 16 + fr;
            bf16x8 bh8 = *(bf16x8*)&Kh[krow][kcol];
            bf16x8 bl8 = *(bf16x8*)&Kl[krow][kcol];
#pragma unroll
            for (int mi = 0; mi < 4; ++mi) {
                acc[mi] = MFMA(qah[ks][mi], bh8, acc[mi]);
                acc[mi] = MFMA(qah[ks][mi], bl8, acc[mi]);
                acc[mi] = MFMA(qal[ks][mi], bh8, acc[mi]);
            }
        }
#pragma unroll
        for (int mi = 0; mi < 4; ++mi)
#pragma unroll
            for (int r = 0; r < 4; ++r)
                rmax[mi][r] = fmaxf(rmax[mi][r], acc[mi][r]);
    }

    // reduce over the 16 k-columns held across lanes of each 16-group
#pragma unroll
    for (int mi = 0; mi < 4; ++mi)
#pragma unroll
        for (int r = 0; r < 4; ++r) {
            float v = rmax[mi][r];
            v = fmaxf(v, __shfl_xor(v, 1));
            v = fmaxf(v, __shfl_xor(v, 2));
            v = fmaxf(v, __shfl_xor(v, 4));
            v = fmaxf(v, __shfl_xor(v, 8));
            rmax[mi][r] = v;
        }
    if ((lane & 15) == 0) {
        int quad = lane >> 4;
#pragma unroll
        for (int mi = 0; mi < 4; ++mi)
#pragma unroll
            for (int r = 0; r < 4; ++r)
                Mred[mi * 16 + quad * 4 + r][wave] = rmax[mi][r];
    }
    __syncthreads();
    if (tid < 64) {
        float mx = fmaxf(fmaxf(Mred[tid][0], Mred[tid][1]),
                         fmaxf(Mred[tid][2], Mred[tid][3]));
        float dot = 0.f;
#pragma unroll 4
        for (int d = 0; d < 64; ++d)
            dot = fmaf(bf2f(Qh[tid][d]) + bf2f(Ql[tid][d]), km[d], dot);
        Mout[(size_t)bh * L_ + q0 + tid] = mx - dot;
    }
}

// ---------------------------------------------------------------
// top-35 of M[1024] per (b,h)
// ---------------------------------------------------------------
__global__ __launch_bounds__(256) void topk35(
    const float* __restrict__ Min, int* __restrict__ idx_out)
{
    const int bh = blockIdx.x;
    const int tid = threadIdx.x;
    __shared__ float vals[1024];
    __shared__ float wv[4];
    __shared__ int wi[4];
    for (int i = tid; i < 1024; i += 256) vals[i] = Min[(size_t)bh * 1024 + i];
    __syncthreads();
    for (int it = 0; it < U_; ++it) {
        float bv = -INFINITY; int bi = 1 << 30;
        for (int i = tid; i < 1024; i += 256) {
            float x = vals[i];
            if (x > bv) { bv = x; bi = i; }
        }
#pragma unroll
        for (int off = 32; off; off >>= 1) {
            float ov = __shfl_down(bv, off);
            int   oi = __shfl_down(bi, off);
            if (ov > bv || (ov == bv && oi < bi)) { bv = ov; bi = oi; }
        }
        if ((tid & 63) == 0) { wv[tid >> 6] = bv; wi[tid >> 6] = bi; }
        __syncthreads();
        if (tid == 0) {
#pragma unroll
            for (int w = 1; w < 4; ++w) {
                if (wv[w] > bv || (wv[w] == bv && wi[w] < bi)) { bv = wv[w]; bi = wi[w]; }
            }
            idx_out[bh * U_ + it] = bi;
            vals[bi] = -INFINITY;
        }
        __syncthreads();
    }
}

// ---------------------------------------------------------------
// S[u][k] = (q[idx_u] . k_k)/8 masked; grid (128 bh, 8 key-chunks)
// ---------------------------------------------------------------
__global__ __launch_bounds__(256) void scores_red(
    const unsigned short* __restrict__ qhi, const unsigned short* __restrict__ qlo,
    const unsigned short* __restrict__ khi, const unsigned short* __restrict__ klo,
    const int* __restrict__ idx, const int* __restrict__ mask,
    float* __restrict__ S)
{
    __shared__ float Qs[64][36];
    __shared__ float Ks[64][68];
    const int bh = blockIdx.x;
    const int b = bh >> 3;
    const int tid = threadIdx.x;
    const int tk = tid & 63, tg = tid >> 6;

    for (int t = tid; t < 36 * 64; t += 256) {
        int u = t >> 6, d = t & 63;
        float val = 0.f;
        if (u < U_) {
            int l = idx[bh * U_ + u];
            size_t off = ((size_t)bh * L_ + l) * 64 + d;
            val = bf2f(qhi[off]) + bf2f(qlo[off]);
        }
        Qs[d][u] = val;
    }

    const size_t kb = (size_t)bh * L_ * 64;
    const int sr = tid >> 2, sc = (tid & 3) * 16;
    float acc[9];
    const int kt0 = blockIdx.y * 2;
    for (int ki = 0; ki < 2; ++ki) {
        int kt = kt0 + ki;
        if (ki) __syncthreads();
        {
            size_t off = kb + (size_t)(kt * 64 + sr) * 64 + sc;
            uint4 h0 = *(const uint4*)(khi + off);
            uint4 h1 = *(const uint4*)(khi + off + 8);
            uint4 l0 = *(const uint4*)(klo + off);
            uint4 l1 = *(const uint4*)(klo + off + 8);
            unsigned short hv[16], lv[16];
            *(uint4*)hv = h0; *(uint4*)(hv + 8) = h1;
            *(uint4*)lv = l0; *(uint4*)(lv + 8) = l1;
#pragma unroll
            for (int i = 0; i < 16; ++i)
                Ks[sc + i][sr] = bf2f(hv[i]) + bf2f(lv[i]);
        }
        __syncthreads();
#pragma unroll
        for (int j = 0; j < 9; j++) acc[j] = 0.f;
#pragma unroll 4
        for (int d = 0; d < 64; ++d) {
            float kv = Ks[d][tk];
#pragma unroll
            for (int j = 0; j < 9; j++) acc[j] = fmaf(Qs[d][tg + 4 * j], kv, acc[j]);
        }
        const int kcol = kt * 64 + tk;
        const bool msk = (mask[b * L_ + kcol] == 0);
#pragma unroll
        for (int j = 0; j < 9; j++) {
            int u = tg + 4 * j;
            if (u < U_)
                S[((size_t)bh * U_ + u) * 1024 + kcol] = msk ? -INFINITY : acc[j] * 0.125f;
        }
    }
}

// ---------------------------------------------------------------
// softmax over 1024 per row; grid 4480 rows
// ---------------------------------------------------------------
__global__ __launch_bounds__(256) void softmax_rows(float* __restrict__ S)
{
    const size_t base = (size_t)blockIdx.x * 1024;
    const int tid = threadIdx.x;
    __shared__ float redm[4];
    __shared__ float reds[4];
    float4 v = *(const float4*)(S + base + tid * 4);
    float mx = fmaxf(fmaxf(v.x, v.y), fmaxf(v.z, v.w));
#pragma unroll
    for (int off = 32; off; off >>= 1) mx = fmaxf(mx, __shfl_down(mx, off));
    if ((tid & 63) == 0) redm[tid >> 6] = mx;
    __syncthreads();
    mx = fmaxf(fmaxf(redm[0], redm[1]), fmaxf(redm[2], redm[3]));
    float e0 = __expf(v.x - mx), e1 = __expf(v.y - mx);
    float e2 = __expf(v.z - mx), e3 = __expf(v.w - mx);
    float s = e0 + e1 + e2 + e3;
#pragma unroll
    for (int off = 32; off; off >>= 1) s += __shfl_down(s, off);
    if ((tid & 63) == 0) reds[tid >> 6] = s;
    __syncthreads();
    s = reds[0] + reds[1] + reds[2] + reds[3];
    const float inv = 1.0f / s;
    float4 o; o.x = e0 * inv; o.y = e1 * inv; o.z = e2 * inv; o.w = e3 * inv;
    *(float4*)(S + base + tid * 4) = o;
}

// ---------------------------------------------------------------
// ctx partials: grid (128 bh, 8 kc)
// ---------------------------------------------------------------
__global__ __launch_bounds__(256) void ctx_partial(
    const float* __restrict__ S, const float* __restrict__ v,
    float* __restrict__ ctxp)
{
    __shared__ float Vs[128][68];
    __shared__ float Wt[36][128];
    const int bh = blockIdx.x, kc = blockIdx.y;
    const int tid = threadIdx.x;
    const int td = tid & 63, tg = tid >> 6;
    const int lr = tid >> 2, lc0 = (tid & 3) * 16;

    const float* vbase = v + ((size_t)bh * L_ + kc * 128) * 64;
    const float* Sbase = S + (size_t)bh * U_ * 1024 + kc * 128;

#pragma unroll
    for (int hh = 0; hh < 2; ++hh) {
        int row = lr + hh * 64;
        const float* src = vbase + (size_t)row * 64 + lc0;
        *(float4*)&Vs[row][lc0 + 0]  = *(const float4*)(src + 0);
        *(float4*)&Vs[row][lc0 + 4]  = *(const float4*)(src + 4);
        *(float4*)&Vs[row][lc0 + 8]  = *(const float4*)(src + 8);
        *(float4*)&Vs[row][lc0 + 12] = *(const float4*)(src + 12);
    }
    for (int t = tid; t < 36 * 128; t += 256) {
        int u = t >> 7, kk = t & 127;
        Wt[u][kk] = (u < U_) ? Sbase[(size_t)u * 1024 + kk] : 0.f;
    }
    __syncthreads();

    float acc[9];
#pragma unroll
    for (int j = 0; j < 9; j++) acc[j] = 0.f;
#pragma unroll 2
    for (int kk = 0; kk < 128; ++kk) {
        float vv = Vs[kk][td];
#pragma unroll
        for (int j = 0; j < 9; j++) acc[j] = fmaf(Wt[tg + 4 * j][kk], vv, acc[j]);
    }
#pragma unroll
    for (int j = 0; j < 9; j++) {
        int u = tg + 4 * j;
        if (u < U_)
            ctxp[((size_t)(kc * 128 + bh) * 36 + u) * 64 + td] = acc[j];
    }
}

// ---------------------------------------------------------------
// ctxd[bh][u][d] = sum_kc ctxp - vmean[bh][d] ; grid 1120 x 256
// ---------------------------------------------------------------
__global__ __launch_bounds__(256) void ctx_reduce_diff(
    const float* __restrict__ ctxp, const float* __restrict__ vmean,
    float* __restrict__ ctxd)
{
    const int i = blockIdx.x * 256 + threadIdx.x;   // 128*35*64 = 286720
    const int d = i & 63;
    const int rest = i >> 6;
    const int u = rest % U_;
    const int bh = rest / U_;
    float s = 0.f;
#pragma unroll
    for (int kc = 0; kc < 8; ++kc)
        s += ctxp[((size_t)(kc * 128 + bh) * 36 + u) * 64 + d];
    ctxd[i] = s - vmean[(size_t)bh * 64 + d];
}

// ---------------------------------------------------------------
// obase[b][n] = dot(xbar[b], Wo[n]) + bo[n] ; grid 128 (16 b x 8 nchunk)
// ---------------------------------------------------------------
__global__ __launch_bounds__(256) void vmean_proj(
    const float* __restrict__ vmean, const float* __restrict__ Wo,
    const float* __restrict__ bo, float* __restrict__ obase)
{
    const int b = blockIdx.x >> 3, n0 = (blockIdx.x & 7) * 64;
    const int tid = threadIdx.x;
    __shared__ float xbar[512];
    __shared__ float psum[64][5];
    for (int i = tid; i < 512; i += 256)
        xbar[i] = vmean[(size_t)(b * 8 + (i >> 6)) * 64 + (i & 63)];
    __syncthreads();
    const int n = n0 + (tid >> 2), fq = (tid & 3) * 128;
    float s = 0.f;
    for (int f = 0; f < 128; f += 4) {
        float4 w = *(const float4*)(Wo + (size_t)n * 512 + fq + f);
        s += xbar[fq + f] * w.x + xbar[fq + f + 1] * w.y +
             xbar[fq + f + 2] * w.z + xbar[fq + f + 3] * w.w;
    }
    psum[tid >> 2][tid & 3] = s;
    __syncthreads();
    if (tid < 64)
        obase[(size_t)b * 512 + n0 + tid] =
            psum[tid][0] + psum[tid][1] + psum[tid][2] + psum[tid][3] + bo[n0 + tid];
}

// ---------------------------------------------------------------
// out[b][l][:] = obase[b][:] ; grid 8192 x 256 (float4)
// ---------------------------------------------------------------
__global__ void broadcast_out(const float* __restrict__ obase, float* __restrict__ out)
{
    const size_t e = ((size_t)blockIdx.x * 256 + threadIdx.x) * 4;
    const int n = (int)(e & 511);
    const int b = (int)(e >> 19);
    *(float4*)(out + e) = *(const float4*)(obase + (b << 9) + n);
}

// ---------------------------------------------------------------
// out[b][l_u][n] += ctxd[bh][u] . Wo[n][h*64..]
// grid (128 bh, 4 col-chunks) x 128 threads; one column n per thread.
// ---------------------------------------------------------------
__global__ __launch_bounds__(128) void delta_out(
    const float* __restrict__ ctxd, const int* __restrict__ idx,
    const float* __restrict__ Wo, float* __restrict__ out)
{
    const int bh = blockIdx.x, b = bh >> 3, h = bh & 7;
    const int tid = threadIdx.x;
    const int n = blockIdx.y * 128 + tid;
    __shared__ float sd[U_][64];
    __shared__ int ls[U_];
    if (tid < U_) ls[tid] = idx[bh * U_ + tid];
    for (int t = tid; t < U_ * 64; t += 128)
        sd[t >> 6][t & 63] = ctxd[(size_t)bh * U_ * 64 + t];

    float4 w[16];
    const float* wp = Wo + (size_t)n * 512 + h * 64;
#pragma unroll
    for (int jc = 0; jc < 16; ++jc) w[jc] = *(const float4*)(wp + jc * 4);
    __syncthreads();

    for (int u = 0; u < U_; ++u) {
        float acc = 0.f;
#pragma unroll
        for (int jc = 0; jc < 16; ++jc) {
            float4 dv = *(const float4*)&sd[u][jc * 4];
            acc = fmaf(dv.w, w[jc].w, fmaf(dv.z, w[jc].z,
                  fmaf(dv.y, w[jc].y, fmaf(dv.x, w[jc].x, acc))));
        }
        atomicAdd(out + ((size_t)b * L_ + ls[u]) * 512 + n, acc);
    }
}

// ---------------------------------------------------------------
extern "C" void kernel_launch(void* const* d_in, const int* in_sizes, int n_in,
                              void* d_out, int out_size, void* d_ws, size_t ws_size,
                              hipStream_t stream)
{
    (void)in_sizes; (void)n_in; (void)out_size; (void)ws_size;
    const float* query = (const float*)d_in[0];
    const float* key   = (const float*)d_in[1];
    const float* value = (const float*)d_in[2];
    const int*   mask  = (const int*)d_in[3];
    const float* Wq = (const float*)d_in[4];
    const float* bq = (const float*)d_in[5];
    const float* Wk = (const float*)d_in[6];
    const float* bk = (const float*)d_in[7];
    const float* Wv = (const float*)d_in[8];
    const float* bvp = (const float*)d_in[9];
    const float* Wo = (const float*)d_in[10];
    const float* bo = (const float*)d_in[11];
    float* out = (float*)d_out;

    float* ws = (float*)d_ws;
    float* v      = ws + OFF_V;
    unsigned short* q_hi = (unsigned short*)(ws + OFF_QHI);
    unsigned short* q_lo = (unsigned short*)(ws + OFF_QLO);
    unsigned short* k_hi = (unsigned short*)(ws + OFF_KHI);
    unsigned short* k_lo = (unsigned short*)(ws + OFF_KLO);
    float* ctxp   = ws + OFF_CTXP;
    float* S      = ws + OFF_S;
    float* Marr   = ws + OFF_M;
    float* kmean  = ws + OFF_KMEAN;
    float* vmean  = ws + OFF_VMEAN;
    float* ctxd   = ws + OFF_CTXD;
    int*   idx    = (int*)(ws + OFF_IDX);
    float* obase  = ws + OFF_OBASE;
    unsigned short* wqh = (unsigned short*)(ws + OFF_WQH);
    unsigned short* wql = (unsigned short*)(ws + OFF_WQL);
    unsigned short* wkh = (unsigned short*)(ws + OFF_WKH);
    unsigned short* wkl = (unsigned short*)(ws + OFF_WKL);
    unsigned short* wvh = (unsigned short*)(ws + OFF_WVH);
    unsigned short* wvl = (unsigned short*)(ws + OFF_WVL);

    // weight splits (fused)
    split_w3<<<3072, 256, 0, stream>>>(Wq, Wk, Wv, wqh, wql, wkh, wkl, wvh, wvl);

    // projections: single fused dispatch (z = q/k/v) — 1536 blocks fills the
    // LDS-limited 4 blocks/CU instead of 3 launches at 2 blocks/CU.
    gemm_qkv<<<dim3(128, 4, 3), 256, 0, stream>>>(
        query, key, value,
        wqh, wql, wkh, wkl, wvh, wvl,
        bq, bk, bvp,
        v, q_hi, q_lo, k_hi, k_lo);

    // per-(b,h) means (fused) + base output row
    means_fused<<<256, 256, 0, stream>>>(k_hi, k_lo, v, kmean, vmean);
    vmean_proj<<<128, 256, 0, stream>>>(vmean, Wo, bo, obase);

    // sparsity measure M (MFMA, XCD-swizzled, hoisted-Q, 64-row tiles)
    qk_rowmax_mfma<<<dim3(128, 16), 256, 0, stream>>>(q_hi, q_lo, k_hi, k_lo, kmean, Marr);
    topk35<<<128, 256, 0, stream>>>(Marr, idx);

    // reduced attention (K-split for parallelism)
    scores_red<<<dim3(128, 8), 256, 0, stream>>>(q_hi, q_lo, k_hi, k_lo, idx, mask, S);
    softmax_rows<<<B_ * H_ * U_, 256, 0, stream>>>(S);
    ctx_partial<<<dim3(128, 8), 256, 0, stream>>>(S, v, ctxp);   // ctxp aliases q_hi (dead)
    ctx_reduce_diff<<<1120, 256, 0, stream>>>(ctxp, vmean, ctxd);

    // output = broadcast base row + sparse delta (replaces full Wo GEMM)
    broadcast_out<<<8192, 256, 0, stream>>>(obase, out);
    delta_out<<<dim3(128, 4), 128, 0, stream>>>(ctxd, idx, Wo, out);
}

// Round 2
// 452.644 us; speedup vs baseline: 1.0258x; 1.0191x over previous
//
#include <hip/hip_runtime.h>
#include <math.h>

#define B_ 16
#define L_ 1024
#define H_ 8
#define U_ 35

typedef float f32x4 __attribute__((ext_vector_type(4)));
typedef short bf16x8 __attribute__((ext_vector_type(8)));

__device__ __forceinline__ unsigned short f2bf(float x) {
    unsigned int u = __float_as_uint(x);
    u += 0x7FFFu + ((u >> 16) & 1u);      // round-to-nearest-even
    return (unsigned short)(u >> 16);
}
__device__ __forceinline__ float bf2f(unsigned short b) {
    return __uint_as_float(((unsigned int)b) << 16);
}

// async global->LDS, 16B per lane (guide §5: the compiler never auto-emits this)
__device__ __forceinline__ void gl_lds16(const void* g, void* l) {
    __builtin_amdgcn_global_load_lds(
        (const __attribute__((address_space(1))) unsigned int*)g,
        (__attribute__((address_space(3))) unsigned int*)l, 16, 0, 0);
}

#define MFMA(a, b, c) __builtin_amdgcn_mfma_f32_16x16x32_bf16((a), (b), (c), 0, 0, 0)

// ---------------- workspace layout (float-element offsets) ----------------
#define OFF_V      ((size_t)0)           // 8388608 f
#define OFF_QHI    ((size_t)8388608)     // 4194304
#define OFF_QLO    ((size_t)12582912)    // 4194304
#define OFF_CTXP   OFF_QHI               // ctx partials alias q_hi (dead after scores)
#define OFF_KHI    ((size_t)16777216)    // 4194304
#define OFF_KLO    ((size_t)20971520)    // 4194304
#define OFF_S      ((size_t)25165824)    // 4587520
#define OFF_WQH    OFF_S                 // W splits alias S (dead before scores)
#define OFF_WQL    ((size_t)(OFF_S + 131072))
#define OFF_WKH    ((size_t)(OFF_S + 262144))
#define OFF_WKL    ((size_t)(OFF_S + 393216))
#define OFF_WVH    ((size_t)(OFF_S + 524288))
#define OFF_WVL    ((size_t)(OFF_S + 655360))
#define OFF_M      ((size_t)29753344)    // 131072
#define OFF_KMEAN  ((size_t)29884416)    // 8192
#define OFF_VMEAN  ((size_t)29892608)    // 8192
#define OFF_CTXD   ((size_t)29900800)    // 286720 (ctx - vmean diffs)
#define OFF_IDX    ((size_t)30187520)    // 4480
#define OFF_OBASE  ((size_t)30192000)    // 8192 (per-b base output row)
// end ~30.2M f = ~121 MB

// ---------------------------------------------------------------
// split Wq/Wk/Wv fp32 -> hi/lo bf16; grid 3072 x 256
// ---------------------------------------------------------------
__global__ __launch_bounds__(256) void split_w3(
    const float* __restrict__ Wq, const float* __restrict__ Wk,
    const float* __restrict__ Wv,
    unsigned short* __restrict__ wqh, unsigned short* __restrict__ wql,
    unsigned short* __restrict__ wkh, unsigned short* __restrict__ wkl,
    unsigned short* __restrict__ wvh, unsigned short* __restrict__ wvl)
{
    const int w = blockIdx.x >> 10;
    const int i = (blockIdx.x & 1023) * 256 + threadIdx.x;
    const float* W = (w == 0) ? Wq : (w == 1) ? Wk : Wv;
    unsigned short* hi = (w == 0) ? wqh : (w == 1) ? wkh : wvh;
    unsigned short* lo = (w == 0) ? wql : (w == 1) ? wkl : wvl;
    float x = W[i];
    unsigned short h = f2bf(x);
    hi[i] = h;
    lo[i] = f2bf(x - bf2f(h));
}

// ---------------------------------------------------------------
// Fused bf16x2 MFMA GEMM for all three projections (z = q/k/v).
// R2 changes vs R1 (counters: WRITE 131MB vs 64 ideal; B staged via VGPR):
//  - B (weights, already bf16 hi/lo) staged with global_load_lds width=16
//    into linear [128][32] LDS tiles (m97 pattern) — async, drains behind
//    the A f2bf-conversion VALU.
//  - Epilogue stages the 128x64 per-head output tile in LDS (aliasing the
//    dead staging buffers) and stores fully-coalesced 16B/lane — removes
//    the 2x partial-line write amplification of scattered ushort stores.
// MFMA sequence / rounding bit-identical to R1 -> absmax must not move.
// ---------------------------------------------------------------
__global__ __launch_bounds__(256) void gemm_qkv(
    const float* __restrict__ Aq, const float* __restrict__ Ak,
    const float* __restrict__ Av,
    const unsigned short* __restrict__ wqh, const unsigned short* __restrict__ wql,
    const unsigned short* __restrict__ wkh, const unsigned short* __restrict__ wkl,
    const unsigned short* __restrict__ wvh, const unsigned short* __restrict__ wvl,
    const float* __restrict__ bqp, const float* __restrict__ bkp,
    const float* __restrict__ bvp,
    float* __restrict__ vout,
    unsigned short* __restrict__ qhi_o, unsigned short* __restrict__ qlo_o,
    unsigned short* __restrict__ khi_o, unsigned short* __restrict__ klo_o)
{
    // one raw LDS pool, aliased: staging (36864 B) then epilogue Cf (34816 B)
    __shared__ __align__(16) unsigned char smem[36864];
    unsigned short (*Ah)[40] = (unsigned short (*)[40])(smem);            // 10240 B
    unsigned short (*Al)[40] = (unsigned short (*)[40])(smem + 10240);    // 10240 B
    unsigned short (*Bh)[32] = (unsigned short (*)[32])(smem + 20480);    //  8192 B
    unsigned short (*Bl)[32] = (unsigned short (*)[32])(smem + 28672);    //  8192 B
    float (*Cf)[68] = (float (*)[68])(smem);                              // 34816 B

    const int z = blockIdx.z;
    const float* A = (z == 0) ? Aq : (z == 1) ? Ak : Av;
    const unsigned short* Whi = (z == 0) ? wqh : (z == 1) ? wkh : wvh;
    const unsigned short* Wlo = (z == 0) ? wql : (z == 1) ? wkl : wvl;
    const float* bias = (z == 0) ? bqp : (z == 1) ? bkp : bvp;
    unsigned short* ohi = (z == 0) ? qhi_o : (z == 1) ? khi_o : nullptr;
    unsigned short* olo = (z == 0) ? qlo_o : (z == 1) ? klo_o : nullptr;

    const int tid = threadIdx.x, lane = tid & 63, wave = tid >> 6;
    const int m0 = blockIdx.x * 128, n0 = blockIdx.y * 128;
    const int wm = (wave >> 1) * 64, wn = (wave & 1) * 64;

    f32x4 zero4 = {0.f, 0.f, 0.f, 0.f};
    f32x4 acc[4][4];
#pragma unroll
    for (int i = 0; i < 4; i++)
#pragma unroll
        for (int j = 0; j < 4; j++) acc[i][j] = zero4;

    const int ar = tid >> 3, ac = (tid & 7) * 4;
    const int kc = (lane >> 4) * 8;
    const int fr = lane & 15;
    // B gload mapping: issue i covers rows i*64..i*64+63 of the [128][32] tile
    const int btr = tid >> 2;            // tile row within issue
    const int btc = (tid & 3) * 8;       // elem col
    const int bldsoff = tid * 16;        // lds byte offset within issue

    for (int k0 = 0; k0 < 512; k0 += 32) {
        if (k0) __syncthreads();
        // --- B: async global->LDS (2 issues each for hi/lo), no VGPR roundtrip
#pragma unroll
        for (int i = 0; i < 2; ++i) {
            size_t gb = (size_t)(n0 + i * 64 + btr) * 512 + k0 + btc;
            gl_lds16(Whi + gb, (unsigned char*)Bh + i * 4096 + bldsoff);
            gl_lds16(Wlo + gb, (unsigned char*)Bl + i * 4096 + bldsoff);
        }
        // --- A: fp32 load + hi/lo split (VALU overlaps the async B loads)
#pragma unroll
        for (int p = 0; p < 4; ++p) {
            float4 a4 = *(const float4*)(A + (size_t)(m0 + ar + p * 32) * 512 + k0 + ac);
            ushort4 h4, l4;
            h4.x = f2bf(a4.x); l4.x = f2bf(a4.x - bf2f(h4.x));
            h4.y = f2bf(a4.y); l4.y = f2bf(a4.y - bf2f(h4.y));
            h4.z = f2bf(a4.z); l4.z = f2bf(a4.z - bf2f(h4.z));
            h4.w = f2bf(a4.w); l4.w = f2bf(a4.w - bf2f(h4.w));
            *(ushort4*)&Ah[ar + p * 32][ac] = h4;
            *(ushort4*)&Al[ar + p * 32][ac] = l4;
        }
        __syncthreads();   // drains vmcnt (gload_lds) + lgkmcnt (ds_write)

        bf16x8 ah[4], al[4];
#pragma unroll
        for (int mi = 0; mi < 4; ++mi) {
            int row = wm + mi * 16 + fr;
            ah[mi] = *(bf16x8*)&Ah[row][kc];
            al[mi] = *(bf16x8*)&Al[row][kc];
        }
#pragma unroll
        for (int ni = 0; ni < 4; ++ni) {
            int rn = wn + ni * 16 + fr;
            bf16x8 bh8 = *(bf16x8*)&Bh[rn][kc];
            bf16x8 bl8 = *(bf16x8*)&Bl[rn][kc];
#pragma unroll
            for (int mi = 0; mi < 4; ++mi) {
                acc[mi][ni] = MFMA(ah[mi], bh8, acc[mi][ni]);
                acc[mi][ni] = MFMA(ah[mi], bl8, acc[mi][ni]);
                acc[mi][ni] = MFMA(al[mi], bh8, acc[mi][ni]);
            }
        }
    }

    // ---------------- epilogue: LDS-staged, coalesced stores ----------------
    const int col = lane & 15, rq = (lane >> 4) * 4;
    const int b_ = m0 >> 10;       // 128-row tile lies within one b
    const int l0 = m0 & 1023;

#pragma unroll
    for (int half = 0; half < 2; ++half) {
        __syncthreads();           // staging buffers dead / previous half stored
        if ((wave & 1) == half) {  // waves holding cols [half*64, half*64+64)
#pragma unroll
            for (int ni = 0; ni < 4; ++ni) {
                float bn = bias[n0 + half * 64 + ni * 16 + col];
#pragma unroll
                for (int mi = 0; mi < 4; ++mi)
#pragma unroll
                    for (int r = 0; r < 4; ++r)
                        Cf[wm + mi * 16 + rq + r][ni * 16 + col] = acc[mi][ni][r] + bn;
            }
        }
        __syncthreads();
        const int h_ = (n0 >> 6) + half;
        const size_t plane = ((size_t)(b_ * H_ + h_) * L_ + l0) * 64;
        if (z == 2) {
            // fp32 v: thread handles 32 consecutive f32 of the 8192-elem plane
            const int r = tid >> 1, d0 = (tid & 1) * 32;
#pragma unroll
            for (int j = 0; j < 8; ++j) {
                float4 val = *(const float4*)&Cf[r][d0 + j * 4];
                *(float4*)(vout + plane + (size_t)r * 64 + d0 + j * 4) = val;
            }
        } else {
            // q/k: split to hi/lo at store time; 16B stores
            const int r = tid >> 1, d0 = (tid & 1) * 32;
#pragma unroll
            for (int c = 0; c < 4; ++c) {
                union { unsigned short s[8]; uint4 u; } ph, pl;
#pragma unroll
                for (int j = 0; j < 8; ++j) {
                    float x = Cf[r][d0 + c * 8 + j];
                    unsigned short h = f2bf(x);
                    ph.s[j] = h;
                    pl.s[j] = f2bf(x - bf2f(h));
                }
                *(uint4*)(ohi + plane + (size_t)r * 64 + d0 + c * 8) = ph.u;
                *(uint4*)(olo + plane + (size_t)r * 64 + d0 + c * 8) = pl.u;
            }
        }
    }
}

// ---------------------------------------------------------------
// fused means: blocks 0..127 -> kmean (from k hi/lo), 128..255 -> vmean (fp32)
// ---------------------------------------------------------------
__global__ __launch_bounds__(256) void means_fused(
    const unsigned short* __restrict__ khi, const unsigned short* __restrict__ klo,
    const float* __restrict__ v, float* __restrict__ kmean, float* __restrict__ vmean)
{
    const int which = blockIdx.x >> 7;
    const int bh = blockIdx.x & 127;
    const int d = threadIdx.x & 63, g = threadIdx.x >> 6;
    __shared__ float red[4][64];
    float s = 0.f;
    if (which == 0) {
        size_t base = ((size_t)bh * L_ + g * 256) * 64 + d;
#pragma unroll 8
        for (int l = 0; l < 256; l++) {
            size_t o = base + (size_t)l * 64;
            s += bf2f(khi[o]) + bf2f(klo[o]);
        }
    } else {
        const float* p = v + ((size_t)bh * L_ + g * 256) * 64 + d;
#pragma unroll 8
        for (int l = 0; l < 256; l++) s += p[(size_t)l * 64];
    }
    red[g][d] = s;
    __syncthreads();
    if (threadIdx.x < 64) {
        const int dd = threadIdx.x;
        float m = (red[0][dd] + red[1][dd] + red[2][dd] + red[3][dd]) * (1.0f / 1024.0f);
        (which == 0 ? kmean : vmean)[(size_t)bh * 64 + dd] = m;
    }
}

// ---------------------------------------------------------------
// M[l] = max_k(q_l . k_k) - q_l . kmean via bf16x2 MFMA
// grid (128 bh, 16 qt): XCD-local K reuse (bh%8 pins the XCD).
// ---------------------------------------------------------------
__global__ __launch_bounds__(256) void qk_rowmax_mfma(
    const unsigned short* __restrict__ qhi, const unsigned short* __restrict__ qlo,
    const unsigned short* __restrict__ khi, const unsigned short* __restrict__ klo,
    const float* __restrict__ kmean, float* __restrict__ Mout)
{
    __shared__ unsigned short Qh[64][72], Ql[64][72];
    __shared__ unsigned short Kh[64][72], Kl[64][72];
    __shared__ float Mred[64][4];
    __shared__ float km[64];
    const int bh = blockIdx.x, q0 = blockIdx.y * 64;
    const int tid = threadIdx.x, lane = tid & 63, wave = tid >> 6;

    if (tid < 64) km[tid] = kmean[bh * 64 + tid];
    {
        int r = tid >> 2, c = (tid & 3) * 16;
        size_t off = ((size_t)bh * L_ + q0 + r) * 64 + c;
        *(uint4*)&Qh[r][c]     = *(const uint4*)(qhi + off);
        *(uint4*)&Qh[r][c + 8] = *(const uint4*)(qhi + off + 8);
        *(uint4*)&Ql[r][c]     = *(const uint4*)(qlo + off);
        *(uint4*)&Ql[r][c + 8] = *(const uint4*)(qlo + off + 8);
    }

    const size_t kb = (size_t)bh * L_ * 64;
    const int sr = tid >> 2, sc = (tid & 3) * 16;
    const int fr = lane & 15;
    f32x4 zero4 = {0.f, 0.f, 0.f, 0.f};

    // register prefetch of K tile 0 (64 rows)
    uint4 pha, phb, pla, plb;
    {
        size_t off = kb + (size_t)sr * 64 + sc;
        pha = *(const uint4*)(khi + off);  phb = *(const uint4*)(khi + off + 8);
        pla = *(const uint4*)(klo + off);  plb = *(const uint4*)(klo + off + 8);
    }

    __syncthreads();   // Q/km staged

    // hoist Q fragments into registers — invariant across the K loop
    bf16x8 qah[2][4], qal[2][4];
#pragma unroll
    for (int ks = 0; ks < 2; ++ks) {
        int kcol = ks * 32 + (lane >> 4) * 8;
#pragma unroll
        for (int mi = 0; mi < 4; ++mi) {
            qah[ks][mi] = *(bf16x8*)&Qh[mi * 16 + fr][kcol];
            qal[ks][mi] = *(bf16x8*)&Ql[mi * 16 + fr][kcol];
        }
    }

    float rmax[4][4];
#pragma unroll
    for (int mi = 0; mi < 4; ++mi)
#pragma unroll
        for (int r = 0; r < 4; ++r) rmax[mi][r] = -INFINITY;

    for (int kt = 0; kt < 16; ++kt) {
        if (kt) __syncthreads();   // previous tile's readers done
        *(uint4*)&Kh[sr][sc] = pha;  *(uint4*)&Kh[sr][sc + 8] = phb;
        *(uint4*)&Kl[sr][sc] = pla;  *(uint4*)&Kl[sr][sc + 8] = plb;
        __syncthreads();

        if (kt < 15) {   // next-tile loads drain behind the MFMAs
            size_t off = kb + (size_t)((kt + 1) * 64 + sr) * 64 + sc;
            pha = *(const uint4*)(khi + off);  phb = *(const uint4*)(khi + off + 8);
            pla = *(const uint4*)(klo + off);  plb = *(const uint4*)(klo + off + 8);
        }

        f32x4 acc[4];
#pragma unroll
        for (int mi = 0; mi < 4; ++mi) acc[mi] = zero4;

#pragma unroll
        for (int ks = 0; ks < 2; ++ks) {
            int kcol = ks * 32 + (lane >> 4) * 8;
            int krow = wave * 16 + fr;
            bf16x8 bh8 = *(bf16x8*)&Kh[krow][kcol];
            bf16x8 bl8 = *(bf16x8*)&Kl[krow][kcol];
#pragma unroll
            for (int mi = 0; mi < 4; ++mi) {
                acc[mi] = MFMA(qah[ks][mi], bh8, acc[mi]);
                acc[mi] = MFMA(qah[ks][mi], bl8, acc[mi]);
                acc[mi] = MFMA(qal[ks][mi], bh8, acc[mi]);
            }
        }
#pragma unroll
        for (int mi = 0; mi < 4; ++mi)
#pragma unroll
            for (int r = 0; r < 4; ++r)
                rmax[mi][r] = fmaxf(rmax[mi][r], acc[mi][r]);
    }

    // reduce over the 16 k-columns held across lanes of each 16-group
#pragma unroll
    for (int mi = 0; mi < 4; ++mi)
#pragma unroll
        for (int r = 0; r < 4; ++r) {
            float v = rmax[mi][r];
            v = fmaxf(v, __shfl_xor(v, 1));
            v = fmaxf(v, __shfl_xor(v, 2));
            v = fmaxf(v, __shfl_xor(v, 4));
            v = fmaxf(v, __shfl_xor(v, 8));
            rmax[mi][r] = v;
        }
    if ((lane & 15) == 0) {
        int quad = lane >> 4;
#pragma unroll
        for (int mi = 0; mi < 4; ++mi)
#pragma unroll
            for (int r = 0; r < 4; ++r)
                Mred[mi * 16 + quad * 4 + r][wave] = rmax[mi][r];
    }
    __syncthreads();
    if (tid < 64) {
        float mx = fmaxf(fmaxf(Mred[tid][0], Mred[tid][1]),
                         fmaxf(Mred[tid][2], Mred[tid][3]));
        float dot = 0.f;
#pragma unroll 4
        for (int d = 0; d < 64; ++d)
            dot = fmaf(bf2f(Qh[tid][d]) + bf2f(Ql[tid][d]), km[d], dot);
        Mout[(size_t)bh * L_ + q0 + tid] = mx - dot;
    }
}

// ---------------------------------------------------------------
// top-35 of M[1024] per (b,h)
// ---------------------------------------------------------------
__global__ __launch_bounds__(256) void topk35(
    const float* __restrict__ Min, int* __restrict__ idx_out)
{
    const int bh = blockIdx.x;
    const int tid = threadIdx.x;
    __shared__ float vals[1024];
    __shared__ float wv[4];
    __shared__ int wi[4];
    for (int i = tid; i < 1024; i += 256) vals[i] = Min[(size_t)bh * 1024 + i];
    __syncthreads();
    for (int it = 0; it < U_; ++it) {
        float bv = -INFINITY; int bi = 1 << 30;
        for (int i = tid; i < 1024; i += 256) {
            float x = vals[i];
            if (x > bv) { bv = x; bi = i; }
        }
#pragma unroll
        for (int off = 32; off; off >>= 1) {
            float ov = __shfl_down(bv, off);
            int   oi = __shfl_down(bi, off);
            if (ov > bv || (ov == bv && oi < bi)) { bv = ov; bi = oi; }
        }
        if ((tid & 63) == 0) { wv[tid >> 6] = bv; wi[tid >> 6] = bi; }
        __syncthreads();
        if (tid == 0) {
#pragma unroll
            for (int w = 1; w < 4; ++w) {
                if (wv[w] > bv || (wv[w] == bv && wi[w] < bi)) { bv = wv[w]; bi = wi[w]; }
            }
            idx_out[bh * U_ + it] = bi;
            vals[bi] = -INFINITY;
        }
        __syncthreads();
    }
}

// ---------------------------------------------------------------
// S[u][k] = (q[idx_u] . k_k)/8 masked; grid (128 bh, 8 key-chunks)
// ---------------------------------------------------------------
__global__ __launch_bounds__(256) void scores_red(
    const unsigned short* __restrict__ qhi, const unsigned short* __restrict__ qlo,
    const unsigned short* __restrict__ khi, const unsigned short* __restrict__ klo,
    const int* __restrict__ idx, const int* __restrict__ mask,
    float* __restrict__ S)
{
    __shared__ float Qs[64][36];
    __shared__ float Ks[64][68];
    const int bh = blockIdx.x;
    const int b = bh >> 3;
    const int tid = threadIdx.x;
    const int tk = tid & 63, tg = tid >> 6;

    for (int t = tid; t < 36 * 64; t += 256) {
        int u = t >> 6, d = t & 63;
        float val = 0.f;
        if (u < U_) {
            int l = idx[bh * U_ + u];
            size_t off = ((size_t)bh * L_ + l) * 64 + d;
            val = bf2f(qhi[off]) + bf2f(qlo[off]);
        }
        Qs[d][u] = val;
    }

    const size_t kb = (size_t)bh * L_ * 64;
    const int sr = tid >> 2, sc = (tid & 3) * 16;
    float acc[9];
    const int kt0 = blockIdx.y * 2;
    for (int ki = 0; ki < 2; ++ki) {
        int kt = kt0 + ki;
        if (ki) __syncthreads();
        {
            size_t off = kb + (size_t)(kt * 64 + sr) * 64 + sc;
            uint4 h0 = *(const uint4*)(khi + off);
            uint4 h1 = *(const uint4*)(khi + off + 8);
            uint4 l0 = *(const uint4*)(klo + off);
            uint4 l1 = *(const uint4*)(klo + off + 8);
            unsigned short hv[16], lv[16];
            *(uint4*)hv = h0; *(uint4*)(hv + 8) = h1;
            *(uint4*)lv = l0; *(uint4*)(lv + 8) = l1;
#pragma unroll
            for (int i = 0; i < 16; ++i)
                Ks[sc + i][sr] = bf2f(hv[i]) + bf2f(lv[i]);
        }
        __syncthreads();
#pragma unroll
        for (int j = 0; j < 9; j++) acc[j] = 0.f;
#pragma unroll 4
        for (int d = 0; d < 64; ++d) {
            float kv = Ks[d][tk];
#pragma unroll
            for (int j = 0; j < 9; j++) acc[j] = fmaf(Qs[d][tg + 4 * j], kv, acc[j]);
        }
        const int kcol = kt * 64 + tk;
        const bool msk = (mask[b * L_ + kcol] == 0);
#pragma unroll
        for (int j = 0; j < 9; j++) {
            int u = tg + 4 * j;
            if (u < U_)
                S[((size_t)bh * U_ + u) * 1024 + kcol] = msk ? -INFINITY : acc[j] * 0.125f;
        }
    }
}

// ---------------------------------------------------------------
// softmax over 1024 per row; grid 4480 rows
// ---------------------------------------------------------------
__global__ __launch_bounds__(256) void softmax_rows(float* __restrict__ S)
{
    const size_t base = (size_t)blockIdx.x * 1024;
    const int tid = threadIdx.x;
    __shared__ float redm[4];
    __shared__ float reds[4];
    float4 v = *(const float4*)(S + base + tid * 4);
    float mx = fmaxf(fmaxf(v.x, v.y), fmaxf(v.z, v.w));
#pragma unroll
    for (int off = 32; off; off >>= 1) mx = fmaxf(mx, __shfl_down(mx, off));
    if ((tid & 63) == 0) redm[tid >> 6] = mx;
    __syncthreads();
    mx = fmaxf(fmaxf(redm[0], redm[1]), fmaxf(redm[2], redm[3]));
    float e0 = __expf(v.x - mx), e1 = __expf(v.y - mx);
    float e2 = __expf(v.z - mx), e3 = __expf(v.w - mx);
    float s = e0 + e1 + e2 + e3;
#pragma unroll
    for (int off = 32; off; off >>= 1) s += __shfl_down(s, off);
    if ((tid & 63) == 0) reds[tid >> 6] = s;
    __syncthreads();
    s = reds[0] + reds[1] + reds[2] + reds[3];
    const float inv = 1.0f / s;
    float4 o; o.x = e0 * inv; o.y = e1 * inv; o.z = e2 * inv; o.w = e3 * inv;
    *(float4*)(S + base + tid * 4) = o;
}

// ---------------------------------------------------------------
// ctx partials: grid (128 bh, 8 kc)
// ---------------------------------------------------------------
__global__ __launch_bounds__(256) void ctx_partial(
    const float* __restrict__ S, const float* __restrict__ v,
    float* __restrict__ ctxp)
{
    __shared__ float Vs[128][68];
    __shared__ float Wt[36][128];
    const int bh = blockIdx.x, kc = blockIdx.y;
    const int tid = threadIdx.x;
    const int td = tid & 63, tg = tid >> 6;
    const int lr = tid >> 2, lc0 = (tid & 3) * 16;

    const float* vbase = v + ((size_t)bh * L_ + kc * 128) * 64;
    const float* Sbase = S + (size_t)bh * U_ * 1024 + kc * 128;

#pragma unroll
    for (int hh = 0; hh < 2; ++hh) {
        int row = lr + hh * 64;
        const float* src = vbase + (size_t)row * 64 + lc0;
        *(float4*)&Vs[row][lc0 + 0]  = *(const float4*)(src + 0);
        *(float4*)&Vs[row][lc0 + 4]  = *(const float4*)(src + 4);
        *(float4*)&Vs[row][lc0 + 8]  = *(const float4*)(src + 8);
        *(float4*)&Vs[row][lc0 + 12] = *(const float4*)(src + 12);
    }
    for (int t = tid; t < 36 * 128; t += 256) {
        int u = t >> 7, kk = t & 127;
        Wt[u][kk] = (u < U_) ? Sbase[(size_t)u * 1024 + kk] : 0.f;
    }
    __syncthreads();

    float acc[9];
#pragma unroll
    for (int j = 0; j < 9; j++) acc[j] = 0.f;
#pragma unroll 2
    for (int kk = 0; kk < 128; ++kk) {
        float vv = Vs[kk][td];
#pragma unroll
        for (int j = 0; j < 9; j++) acc[j] = fmaf(Wt[tg + 4 * j][kk], vv, acc[j]);
    }
#pragma unroll
    for (int j = 0; j < 9; j++) {
        int u = tg + 4 * j;
        if (u < U_)
            ctxp[((size_t)(kc * 128 + bh) * 36 + u) * 64 + td] = acc[j];
    }
}

// ---------------------------------------------------------------
// ctxd[bh][u][d] = sum_kc ctxp - vmean[bh][d] ; grid 1120 x 256
// ---------------------------------------------------------------
__global__ __launch_bounds__(256) void ctx_reduce_diff(
    const float* __restrict__ ctxp, const float* __restrict__ vmean,
    float* __restrict__ ctxd)
{
    const int i = blockIdx.x * 256 + threadIdx.x;   // 128*35*64 = 286720
    const int d = i & 63;
    const int rest = i >> 6;
    const int u = rest % U_;
    const int bh = rest / U_;
    float s = 0.f;
#pragma unroll
    for (int kc = 0; kc < 8; ++kc)
        s += ctxp[((size_t)(kc * 128 + bh) * 36 + u) * 64 + d];
    ctxd[i] = s - vmean[(size_t)bh * 64 + d];
}

// ---------------------------------------------------------------
// obase[b][n] = dot(xbar[b], Wo[n]) + bo[n] ; grid 128 (16 b x 8 nchunk)
// ---------------------------------------------------------------
__global__ __launch_bounds__(256) void vmean_proj(
    const float* __restrict__ vmean, const float* __restrict__ Wo,
    const float* __restrict__ bo, float* __restrict__ obase)
{
    const int b = blockIdx.x >> 3, n0 = (blockIdx.x & 7) * 64;
    const int tid = threadIdx.x;
    __shared__ float xbar[512];
    __shared__ float psum[64][5];
    for (int i = tid; i < 512; i += 256)
        xbar[i] = vmean[(size_t)(b * 8 + (i >> 6)) * 64 + (i & 63)];
    __syncthreads();
    const int n = n0 + (tid >> 2), fq = (tid & 3) * 128;
    float s = 0.f;
    for (int f = 0; f < 128; f += 4) {
        float4 w = *(const float4*)(Wo + (size_t)n * 512 + fq + f);
        s += xbar[fq + f] * w.x + xbar[fq + f + 1] * w.y +
             xbar[fq + f + 2] * w.z + xbar[fq + f + 3] * w.w;
    }
    psum[tid >> 2][tid & 3] = s;
    __syncthreads();
    if (tid < 64)
        obase[(size_t)b * 512 + n0 + tid] =
            psum[tid][0] + psum[tid][1] + psum[tid][2] + psum[tid][3] + bo[n0 + tid];
}

// ---------------------------------------------------------------
// out[b][l][:] = obase[b][:] ; grid 8192 x 256 (float4)
// ---------------------------------------------------------------
__global__ void broadcast_out(const float* __restrict__ obase, float* __restrict__ out)
{
    const size_t e = ((size_t)blockIdx.x * 256 + threadIdx.x) * 4;
    const int n = (int)(e & 511);
    const int b = (int)(e >> 19);
    *(float4*)(out + e) = *(const float4*)(obase + (b << 9) + n);
}

// ---------------------------------------------------------------
// out[b][l_u][n] += ctxd[bh][u] . Wo[n][h*64..]
// grid (128 bh, 4 col-chunks) x 128 threads; one column n per thread.
// ---------------------------------------------------------------
__global__ __launch_bounds__(128) void delta_out(
    const float* __restrict__ ctxd, const int* __restrict__ idx,
    const float* __restrict__ Wo, float* __restrict__ out)
{
    const int bh = blockIdx.x, b = bh >> 3, h = bh & 7;
    const int tid = threadIdx.x;
    const int n = blockIdx.y * 128 + tid;
    __shared__ float sd[U_][64];
    __shared__ int ls[U_];
    if (tid < U_) ls[tid] = idx[bh * U_ + tid];
    for (int t = tid; t < U_ * 64; t += 128)
        sd[t >> 6][t & 63] = ctxd[(size_t)bh * U_ * 64 + t];

    float4 w[16];
    const float* wp = Wo + (size_t)n * 512 + h * 64;
#pragma unroll
    for (int jc = 0; jc < 16; ++jc) w[jc] = *(const float4*)(wp + jc * 4);
    __syncthreads();

    for (int u = 0; u < U_; ++u) {
        float acc = 0.f;
#pragma unroll
        for (int jc = 0; jc < 16; ++jc) {
            float4 dv = *(const float4*)&sd[u][jc * 4];
            acc = fmaf(dv.w, w[jc].w, fmaf(dv.z, w[jc].z,
                  fmaf(dv.y, w[jc].y, fmaf(dv.x, w[jc].x, acc))));
        }
        atomicAdd(out + ((size_t)b * L_ + ls[u]) * 512 + n, acc);
    }
}

// ---------------------------------------------------------------
extern "C" void kernel_launch(void* const* d_in, const int* in_sizes, int n_in,
                              void* d_out, int out_size, void* d_ws, size_t ws_size,
                              hipStream_t stream)
{
    (void)in_sizes; (void)n_in; (void)out_size; (void)ws_size;
    const float* query = (const float*)d_in[0];
    const float* key   = (const float*)d_in[1];
    const float* value = (const float*)d_in[2];
    const int*   mask  = (const int*)d_in[3];
    const float* Wq = (const float*)d_in[4];
    const float* bq = (const float*)d_in[5];
    const float* Wk = (const float*)d_in[6];
    const float* bk = (const float*)d_in[7];
    const float* Wv = (const float*)d_in[8];
    const float* bvp = (const float*)d_in[9];
    const float* Wo = (const float*)d_in[10];
    const float* bo = (const float*)d_in[11];
    float* out = (float*)d_out;

    float* ws = (float*)d_ws;
    float* v      = ws + OFF_V;
    unsigned short* q_hi = (unsigned short*)(ws + OFF_QHI);
    unsigned short* q_lo = (unsigned short*)(ws + OFF_QLO);
    unsigned short* k_hi = (unsigned short*)(ws + OFF_KHI);
    unsigned short* k_lo = (unsigned short*)(ws + OFF_KLO);
    float* ctxp   = ws + OFF_CTXP;
    float* S      = ws + OFF_S;
    float* Marr   = ws + OFF_M;
    float* kmean  = ws + OFF_KMEAN;
    float* vmean  = ws + OFF_VMEAN;
    float* ctxd   = ws + OFF_CTXD;
    int*   idx    = (int*)(ws + OFF_IDX);
    float* obase  = ws + OFF_OBASE;
    unsigned short* wqh = (unsigned short*)(ws + OFF_WQH);
    unsigned short* wql = (unsigned short*)(ws + OFF_WQL);
    unsigned short* wkh = (unsigned short*)(ws + OFF_WKH);
    unsigned short* wkl = (unsigned short*)(ws + OFF_WKL);
    unsigned short* wvh = (unsigned short*)(ws + OFF_WVH);
    unsigned short* wvl = (unsigned short*)(ws + OFF_WVL);

    // weight splits (fused)
    split_w3<<<3072, 256, 0, stream>>>(Wq, Wk, Wv, wqh, wql, wkh, wkl, wvh, wvl);

    // projections: single fused dispatch (z = q/k/v), async B staging,
    // LDS-staged coalesced epilogue.
    gemm_qkv<<<dim3(128, 4, 3), 256, 0, stream>>>(
        query, key, value,
        wqh, wql, wkh, wkl, wvh, wvl,
        bq, bk, bvp,
        v, q_hi, q_lo, k_hi, k_lo);

    // per-(b,h) means (fused) + base output row
    means_fused<<<256, 256, 0, stream>>>(k_hi, k_lo, v, kmean, vmean);
    vmean_proj<<<128, 256, 0, stream>>>(vmean, Wo, bo, obase);

    // sparsity measure M (MFMA, XCD-swizzled, hoisted-Q, 64-row tiles)
    qk_rowmax_mfma<<<dim3(128, 16), 256, 0, stream>>>(q_hi, q_lo, k_hi, k_lo, kmean, Marr);
    topk35<<<128, 256, 0, stream>>>(Marr, idx);

    // reduced attention (K-split for parallelism)
    scores_red<<<dim3(128, 8), 256, 0, stream>>>(q_hi, q_lo, k_hi, k_lo, idx, mask, S);
    softmax_rows<<<B_ * H_ * U_, 256, 0, stream>>>(S);
    ctx_partial<<<dim3(128, 8), 256, 0, stream>>>(S, v, ctxp);   // ctxp aliases q_hi (dead)
    ctx_reduce_diff<<<1120, 256, 0, stream>>>(ctxp, vmean, ctxd);

    // output = broadcast base row + sparse delta (replaces full Wo GEMM)
    broadcast_out<<<8192, 256, 0, stream>>>(obase, out);
    delta_out<<<dim3(128, 4), 128, 0, stream>>>(ctxd, idx, Wo, out);
}

// Round 3
// 449.464 us; speedup vs baseline: 1.0331x; 1.0071x over previous
//
#include <hip/hip_runtime.h>
#include <math.h>

#define B_ 16
#define L_ 1024
#define H_ 8
#define U_ 35

typedef float f32x4 __attribute__((ext_vector_type(4)));
typedef short bf16x8 __attribute__((ext_vector_type(8)));

__device__ __forceinline__ unsigned short f2bf(float x) {
    unsigned int u = __float_as_uint(x);
    u += 0x7FFFu + ((u >> 16) & 1u);      // round-to-nearest-even
    return (unsigned short)(u >> 16);
}
__device__ __forceinline__ float bf2f(unsigned short b) {
    return __uint_as_float(((unsigned int)b) << 16);
}

// packed f32x2 -> bf16x2 in ONE VALU op (no builtin on gfx950; T12 recipe).
// lo16 = bf16(a), hi16 = bf16(b)
__device__ __forceinline__ unsigned int cvt_pk_bf16(float a, float b) {
    unsigned int r;
    asm("v_cvt_pk_bf16_f32 %0, %1, %2" : "=v"(r) : "v"(a), "v"(b));
    return r;
}

// async global->LDS, 16B per lane (guide §5: the compiler never auto-emits this)
__device__ __forceinline__ void gl_lds16(const void* g, void* l) {
    __builtin_amdgcn_global_load_lds(
        (const __attribute__((address_space(1))) unsigned int*)g,
        (__attribute__((address_space(3))) unsigned int*)l, 16, 0, 0);
}

#define MFMA(a, b, c) __builtin_amdgcn_mfma_f32_16x16x32_bf16((a), (b), (c), 0, 0, 0)

// ---------------- workspace layout (float-element offsets) ----------------
#define OFF_V      ((size_t)0)           // 8388608 f
#define OFF_QHI    ((size_t)8388608)     // 4194304
#define OFF_QLO    ((size_t)12582912)    // 4194304
#define OFF_CTXP   OFF_QHI               // ctx partials alias q_hi (dead after scores)
#define OFF_KHI    ((size_t)16777216)    // 4194304
#define OFF_KLO    ((size_t)20971520)    // 4194304
#define OFF_S      ((size_t)25165824)    // 4587520
#define OFF_WQH    OFF_S                 // W splits alias S (dead before scores)
#define OFF_WQL    ((size_t)(OFF_S + 131072))
#define OFF_WKH    ((size_t)(OFF_S + 262144))
#define OFF_WKL    ((size_t)(OFF_S + 393216))
#define OFF_WVH    ((size_t)(OFF_S + 524288))
#define OFF_WVL    ((size_t)(OFF_S + 655360))
#define OFF_M      ((size_t)29753344)    // 131072
#define OFF_KMEAN  ((size_t)29884416)    // 8192
#define OFF_VMEAN  ((size_t)29892608)    // 8192
#define OFF_CTXD   ((size_t)29900800)    // 286720 (ctx - vmean diffs)
#define OFF_IDX    ((size_t)30187520)    // 4480
#define OFF_OBASE  ((size_t)30192000)    // 8192 (per-b base output row)
// end ~30.2M f = ~121 MB

// ---------------------------------------------------------------
// split Wq/Wk/Wv fp32 -> hi/lo bf16; grid 3072 x 256
// ---------------------------------------------------------------
__global__ __launch_bounds__(256) void split_w3(
    const float* __restrict__ Wq, const float* __restrict__ Wk,
    const float* __restrict__ Wv,
    unsigned short* __restrict__ wqh, unsigned short* __restrict__ wql,
    unsigned short* __restrict__ wkh, unsigned short* __restrict__ wkl,
    unsigned short* __restrict__ wvh, unsigned short* __restrict__ wvl)
{
    const int w = blockIdx.x >> 10;
    const int i = (blockIdx.x & 1023) * 256 + threadIdx.x;
    const float* W = (w == 0) ? Wq : (w == 1) ? Wk : Wv;
    unsigned short* hi = (w == 0) ? wqh : (w == 1) ? wkh : wvh;
    unsigned short* lo = (w == 0) ? wql : (w == 1) ? wkl : wvl;
    float x = W[i];
    unsigned short h = f2bf(x);
    hi[i] = h;
    lo[i] = f2bf(x - bf2f(h));
}

// ---------------------------------------------------------------
// Fused bf16x2 MFMA GEMM for all three projections (z = q/k/v).
// R3 change (counters: MfmaUtil 24% ~= VALUBusy 26% -> A-conversion VALU
// is co-critical with the matrix pipe): packed v_cvt_pk_bf16_f32 for the
// hi/lo split (~3 VALU/elem vs ~7). lo is computed from the exact fp32
// residual, so hi+lo still reconstructs x to ~2^-17 regardless of the
// HW rounding mode -> numerics class unchanged.
// ---------------------------------------------------------------
__global__ __launch_bounds__(256) void gemm_qkv(
    const float* __restrict__ Aq, const float* __restrict__ Ak,
    const float* __restrict__ Av,
    const unsigned short* __restrict__ wqh, const unsigned short* __restrict__ wql,
    const unsigned short* __restrict__ wkh, const unsigned short* __restrict__ wkl,
    const unsigned short* __restrict__ wvh, const unsigned short* __restrict__ wvl,
    const float* __restrict__ bqp, const float* __restrict__ bkp,
    const float* __restrict__ bvp,
    float* __restrict__ vout,
    unsigned short* __restrict__ qhi_o, unsigned short* __restrict__ qlo_o,
    unsigned short* __restrict__ khi_o, unsigned short* __restrict__ klo_o)
{
    // one raw LDS pool, aliased: staging (36864 B) then epilogue Cf (34816 B)
    __shared__ __align__(16) unsigned char smem[36864];
    unsigned short (*Ah)[40] = (unsigned short (*)[40])(smem);            // 10240 B
    unsigned short (*Al)[40] = (unsigned short (*)[40])(smem + 10240);    // 10240 B
    unsigned short (*Bh)[32] = (unsigned short (*)[32])(smem + 20480);    //  8192 B
    unsigned short (*Bl)[32] = (unsigned short (*)[32])(smem + 28672);    //  8192 B
    float (*Cf)[68] = (float (*)[68])(smem);                              // 34816 B

    const int z = blockIdx.z;
    const float* A = (z == 0) ? Aq : (z == 1) ? Ak : Av;
    const unsigned short* Whi = (z == 0) ? wqh : (z == 1) ? wkh : wvh;
    const unsigned short* Wlo = (z == 0) ? wql : (z == 1) ? wkl : wvl;
    const float* bias = (z == 0) ? bqp : (z == 1) ? bkp : bvp;
    unsigned short* ohi = (z == 0) ? qhi_o : (z == 1) ? khi_o : nullptr;
    unsigned short* olo = (z == 0) ? qlo_o : (z == 1) ? klo_o : nullptr;

    const int tid = threadIdx.x, lane = tid & 63, wave = tid >> 6;
    const int m0 = blockIdx.x * 128, n0 = blockIdx.y * 128;
    const int wm = (wave >> 1) * 64, wn = (wave & 1) * 64;

    f32x4 zero4 = {0.f, 0.f, 0.f, 0.f};
    f32x4 acc[4][4];
#pragma unroll
    for (int i = 0; i < 4; i++)
#pragma unroll
        for (int j = 0; j < 4; j++) acc[i][j] = zero4;

    const int ar = tid >> 3, ac = (tid & 7) * 4;
    const int kc = (lane >> 4) * 8;
    const int fr = lane & 15;
    // B gload mapping: issue i covers rows i*64..i*64+63 of the [128][32] tile
    const int btr = tid >> 2;            // tile row within issue
    const int btc = (tid & 3) * 8;       // elem col
    const int bldsoff = tid * 16;        // lds byte offset within issue

    for (int k0 = 0; k0 < 512; k0 += 32) {
        if (k0) __syncthreads();
        // --- B: async global->LDS (2 issues each for hi/lo), no VGPR roundtrip
#pragma unroll
        for (int i = 0; i < 2; ++i) {
            size_t gb = (size_t)(n0 + i * 64 + btr) * 512 + k0 + btc;
            gl_lds16(Whi + gb, (unsigned char*)Bh + i * 4096 + bldsoff);
            gl_lds16(Wlo + gb, (unsigned char*)Bl + i * 4096 + bldsoff);
        }
        // --- A: fp32 load + packed hi/lo split (cvt_pk: ~3 VALU/elem)
#pragma unroll
        for (int p = 0; p < 4; ++p) {
            float4 a4 = *(const float4*)(A + (size_t)(m0 + ar + p * 32) * 512 + k0 + ac);
            unsigned int h01 = cvt_pk_bf16(a4.x, a4.y);
            unsigned int h23 = cvt_pk_bf16(a4.z, a4.w);
            float r0 = a4.x - __uint_as_float(h01 << 16);
            float r1 = a4.y - __uint_as_float(h01 & 0xFFFF0000u);
            float r2 = a4.z - __uint_as_float(h23 << 16);
            float r3 = a4.w - __uint_as_float(h23 & 0xFFFF0000u);
            unsigned int l01 = cvt_pk_bf16(r0, r1);
            unsigned int l23 = cvt_pk_bf16(r2, r3);
            uint2 hh; hh.x = h01; hh.y = h23;
            uint2 ll; ll.x = l01; ll.y = l23;
            *(uint2*)&Ah[ar + p * 32][ac] = hh;
            *(uint2*)&Al[ar + p * 32][ac] = ll;
        }
        __syncthreads();   // drains vmcnt (gload_lds) + lgkmcnt (ds_write)

        bf16x8 ah[4], al[4];
#pragma unroll
        for (int mi = 0; mi < 4; ++mi) {
            int row = wm + mi * 16 + fr;
            ah[mi] = *(bf16x8*)&Ah[row][kc];
            al[mi] = *(bf16x8*)&Al[row][kc];
        }
#pragma unroll
        for (int ni = 0; ni < 4; ++ni) {
            int rn = wn + ni * 16 + fr;
            bf16x8 bh8 = *(bf16x8*)&Bh[rn][kc];
            bf16x8 bl8 = *(bf16x8*)&Bl[rn][kc];
#pragma unroll
            for (int mi = 0; mi < 4; ++mi) {
                acc[mi][ni] = MFMA(ah[mi], bh8, acc[mi][ni]);
                acc[mi][ni] = MFMA(ah[mi], bl8, acc[mi][ni]);
                acc[mi][ni] = MFMA(al[mi], bh8, acc[mi][ni]);
            }
        }
    }

    // ---------------- epilogue: LDS-staged, coalesced stores ----------------
    const int col = lane & 15, rq = (lane >> 4) * 4;
    const int b_ = m0 >> 10;       // 128-row tile lies within one b
    const int l0 = m0 & 1023;

#pragma unroll
    for (int half = 0; half < 2; ++half) {
        __syncthreads();           // staging buffers dead / previous half stored
        if ((wave & 1) == half) {  // waves holding cols [half*64, half*64+64)
#pragma unroll
            for (int ni = 0; ni < 4; ++ni) {
                float bn = bias[n0 + half * 64 + ni * 16 + col];
#pragma unroll
                for (int mi = 0; mi < 4; ++mi)
#pragma unroll
                    for (int r = 0; r < 4; ++r)
                        Cf[wm + mi * 16 + rq + r][ni * 16 + col] = acc[mi][ni][r] + bn;
            }
        }
        __syncthreads();
        const int h_ = (n0 >> 6) + half;
        const size_t plane = ((size_t)(b_ * H_ + h_) * L_ + l0) * 64;
        if (z == 2) {
            // fp32 v: thread handles 32 consecutive f32 of the 8192-elem plane
            const int r = tid >> 1, d0 = (tid & 1) * 32;
#pragma unroll
            for (int j = 0; j < 8; ++j) {
                float4 val = *(const float4*)&Cf[r][d0 + j * 4];
                *(float4*)(vout + plane + (size_t)r * 64 + d0 + j * 4) = val;
            }
        } else {
            // q/k: split to hi/lo at store time (cvt_pk); 16B stores
            const int r = tid >> 1, d0 = (tid & 1) * 32;
#pragma unroll
            for (int c = 0; c < 4; ++c) {
                float x[8];
#pragma unroll
                for (int j = 0; j < 8; ++j) x[j] = Cf[r][d0 + c * 8 + j];
                unsigned int h01 = cvt_pk_bf16(x[0], x[1]);
                unsigned int h23 = cvt_pk_bf16(x[2], x[3]);
                unsigned int h45 = cvt_pk_bf16(x[4], x[5]);
                unsigned int h67 = cvt_pk_bf16(x[6], x[7]);
                float r0 = x[0] - __uint_as_float(h01 << 16);
                float r1 = x[1] - __uint_as_float(h01 & 0xFFFF0000u);
                float r2 = x[2] - __uint_as_float(h23 << 16);
                float r3 = x[3] - __uint_as_float(h23 & 0xFFFF0000u);
                float r4 = x[4] - __uint_as_float(h45 << 16);
                float r5 = x[5] - __uint_as_float(h45 & 0xFFFF0000u);
                float r6 = x[6] - __uint_as_float(h67 << 16);
                float r7 = x[7] - __uint_as_float(h67 & 0xFFFF0000u);
                uint4 ph; ph.x = h01; ph.y = h23; ph.z = h45; ph.w = h67;
                uint4 pl;
                pl.x = cvt_pk_bf16(r0, r1);
                pl.y = cvt_pk_bf16(r2, r3);
                pl.z = cvt_pk_bf16(r4, r5);
                pl.w = cvt_pk_bf16(r6, r7);
                *(uint4*)(ohi + plane + (size_t)r * 64 + d0 + c * 8) = ph;
                *(uint4*)(olo + plane + (size_t)r * 64 + d0 + c * 8) = pl;
            }
        }
    }
}

// ---------------------------------------------------------------
// fused means: blocks 0..127 -> kmean (from k hi/lo), 128..255 -> vmean (fp32)
// ---------------------------------------------------------------
__global__ __launch_bounds__(256) void means_fused(
    const unsigned short* __restrict__ khi, const unsigned short* __restrict__ klo,
    const float* __restrict__ v, float* __restrict__ kmean, float* __restrict__ vmean)
{
    const int which = blockIdx.x >> 7;
    const int bh = blockIdx.x & 127;
    const int d = threadIdx.x & 63, g = threadIdx.x >> 6;
    __shared__ float red[4][64];
    float s = 0.f;
    if (which == 0) {
        size_t base = ((size_t)bh * L_ + g * 256) * 64 + d;
#pragma unroll 8
        for (int l = 0; l < 256; l++) {
            size_t o = base + (size_t)l * 64;
            s += bf2f(khi[o]) + bf2f(klo[o]);
        }
    } else {
        const float* p = v + ((size_t)bh * L_ + g * 256) * 64 + d;
#pragma unroll 8
        for (int l = 0; l < 256; l++) s += p[(size_t)l * 64];
    }
    red[g][d] = s;
    __syncthreads();
    if (threadIdx.x < 64) {
        const int dd = threadIdx.x;
        float m = (red[0][dd] + red[1][dd] + red[2][dd] + red[3][dd]) * (1.0f / 1024.0f);
        (which == 0 ? kmean : vmean)[(size_t)bh * 64 + dd] = m;
    }
}

// ---------------------------------------------------------------
// M[l] = max_k(q_l . k_k) - q_l . kmean via bf16x2 MFMA
// grid (128 bh, 16 qt): XCD-local K reuse (bh%8 pins the XCD).
// ---------------------------------------------------------------
__global__ __launch_bounds__(256) void qk_rowmax_mfma(
    const unsigned short* __restrict__ qhi, const unsigned short* __restrict__ qlo,
    const unsigned short* __restrict__ khi, const unsigned short* __restrict__ klo,
    const float* __restrict__ kmean, float* __restrict__ Mout)
{
    __shared__ unsigned short Qh[64][72], Ql[64][72];
    __shared__ unsigned short Kh[64][72], Kl[64][72];
    __shared__ float Mred[64][4];
    __shared__ float km[64];
    const int bh = blockIdx.x, q0 = blockIdx.y * 64;
    const int tid = threadIdx.x, lane = tid & 63, wave = tid >> 6;

    if (tid < 64) km[tid] = kmean[bh * 64 + tid];
    {
        int r = tid >> 2, c = (tid & 3) * 16;
        size_t off = ((size_t)bh * L_ + q0 + r) * 64 + c;
        *(uint4*)&Qh[r][c]     = *(const uint4*)(qhi + off);
        *(uint4*)&Qh[r][c + 8] = *(const uint4*)(qhi + off + 8);
        *(uint4*)&Ql[r][c]     = *(const uint4*)(qlo + off);
        *(uint4*)&Ql[r][c + 8] = *(const uint4*)(qlo + off + 8);
    }

    const size_t kb = (size_t)bh * L_ * 64;
    const int sr = tid >> 2, sc = (tid & 3) * 16;
    const int fr = lane & 15;
    f32x4 zero4 = {0.f, 0.f, 0.f, 0.f};

    // register prefetch of K tile 0 (64 rows)
    uint4 pha, phb, pla, plb;
    {
        size_t off = kb + (size_t)sr * 64 + sc;
        pha = *(const uint4*)(khi + off);  phb = *(const uint4*)(khi + off + 8);
        pla = *(const uint4*)(klo + off);  plb = *(const uint4*)(klo + off + 8);
    }

    __syncthreads();   // Q/km staged

    // hoist Q fragments into registers — invariant across the K loop
    bf16x8 qah[2][4], qal[2][4];
#pragma unroll
    for (int ks = 0; ks < 2; ++ks) {
        int kcol = ks * 32 + (lane >> 4) * 8;
#pragma unroll
        for (int mi = 0; mi < 4; ++mi) {
            qah[ks][mi] = *(bf16x8*)&Qh[mi * 16 + fr][kcol];
            qal[ks][mi] = *(bf16x8*)&Ql[mi * 16 + fr][kcol];
        }
    }

    float rmax[4][4];
#pragma unroll
    for (int mi = 0; mi < 4; ++mi)
#pragma unroll
        for (int r = 0; r < 4; ++r) rmax[mi][r] = -INFINITY;

    for (int kt = 0; kt < 16; ++kt) {
        if (kt) __syncthreads();   // previous tile's readers done
        *(uint4*)&Kh[sr][sc] = pha;  *(uint4*)&Kh[sr][sc + 8] = phb;
        *(uint4*)&Kl[sr][sc] = pla;  *(uint4*)&Kl[sr][sc + 8] = plb;
        __syncthreads();

        if (kt < 15) {   // next-tile loads drain behind the MFMAs
            size_t off = kb + (size_t)((kt + 1) * 64 + sr) * 64 + sc;
            pha = *(const uint4*)(khi + off);  phb = *(const uint4*)(khi + off + 8);
            pla = *(const uint4*)(klo + off);  plb = *(const uint4*)(klo + off + 8);
        }

        f32x4 acc[4];
#pragma unroll
        for (int mi = 0; mi < 4; ++mi) acc[mi] = zero4;

#pragma unroll
        for (int ks = 0; ks < 2; ++ks) {
            int kcol = ks * 32 + (lane >> 4) * 8;
            int krow = wave * 16 + fr;
            bf16x8 bh8 = *(bf16x8*)&Kh[krow][kcol];
            bf16x8 bl8 = *(bf16x8*)&Kl[krow][kcol];
#pragma unroll
            for (int mi = 0; mi < 4; ++mi) {
                acc[mi] = MFMA(qah[ks][mi], bh8, acc[mi]);
                acc[mi] = MFMA(qah[ks][mi], bl8, acc[mi]);
                acc[mi] = MFMA(qal[ks][mi], bh8, acc[mi]);
            }
        }
#pragma unroll
        for (int mi = 0; mi < 4; ++mi)
#pragma unroll
            for (int r = 0; r < 4; ++r)
                rmax[mi][r] = fmaxf(rmax[mi][r], acc[mi][r]);
    }

    // reduce over the 16 k-columns held across lanes of each 16-group
#pragma unroll
    for (int mi = 0; mi < 4; ++mi)
#pragma unroll
        for (int r = 0; r < 4; ++r) {
            float v = rmax[mi][r];
            v = fmaxf(v, __shfl_xor(v, 1));
            v = fmaxf(v, __shfl_xor(v, 2));
            v = fmaxf(v, __shfl_xor(v, 4));
            v = fmaxf(v, __shfl_xor(v, 8));
            rmax[mi][r] = v;
        }
    if ((lane & 15) == 0) {
        int quad = lane >> 4;
#pragma unroll
        for (int mi = 0; mi < 4; ++mi)
#pragma unroll
            for (int r = 0; r < 4; ++r)
                Mred[mi * 16 + quad * 4 + r][wave] = rmax[mi][r];
    }
    __syncthreads();
    if (tid < 64) {
        float mx = fmaxf(fmaxf(Mred[tid][0], Mred[tid][1]),
                         fmaxf(Mred[tid][2], Mred[tid][3]));
        float dot = 0.f;
#pragma unroll 4
        for (int d = 0; d < 64; ++d)
            dot = fmaf(bf2f(Qh[tid][d]) + bf2f(Ql[tid][d]), km[d], dot);
        Mout[(size_t)bh * L_ + q0 + tid] = mx - dot;
    }
}

// ---------------------------------------------------------------
// top-35 of M[1024] per (b,h)
// ---------------------------------------------------------------
__global__ __launch_bounds__(256) void topk35(
    const float* __restrict__ Min, int* __restrict__ idx_out)
{
    const int bh = blockIdx.x;
    const int tid = threadIdx.x;
    __shared__ float vals[1024];
    __shared__ float wv[4];
    __shared__ int wi[4];
    for (int i = tid; i < 1024; i += 256) vals[i] = Min[(size_t)bh * 1024 + i];
    __syncthreads();
    for (int it = 0; it < U_; ++it) {
        float bv = -INFINITY; int bi = 1 << 30;
        for (int i = tid; i < 1024; i += 256) {
            float x = vals[i];
            if (x > bv) { bv = x; bi = i; }
        }
#pragma unroll
        for (int off = 32; off; off >>= 1) {
            float ov = __shfl_down(bv, off);
            int   oi = __shfl_down(bi, off);
            if (ov > bv || (ov == bv && oi < bi)) { bv = ov; bi = oi; }
        }
        if ((tid & 63) == 0) { wv[tid >> 6] = bv; wi[tid >> 6] = bi; }
        __syncthreads();
        if (tid == 0) {
#pragma unroll
            for (int w = 1; w < 4; ++w) {
                if (wv[w] > bv || (wv[w] == bv && wi[w] < bi)) { bv = wv[w]; bi = wi[w]; }
            }
            idx_out[bh * U_ + it] = bi;
            vals[bi] = -INFINITY;
        }
        __syncthreads();
    }
}

// ---------------------------------------------------------------
// S[u][k] = (q[idx_u] . k_k)/8 masked; grid (128 bh, 8 key-chunks)
// ---------------------------------------------------------------
__global__ __launch_bounds__(256) void scores_red(
    const unsigned short* __restrict__ qhi, const unsigned short* __restrict__ qlo,
    const unsigned short* __restrict__ khi, const unsigned short* __restrict__ klo,
    const int* __restrict__ idx, const int* __restrict__ mask,
    float* __restrict__ S)
{
    __shared__ float Qs[64][36];
    __shared__ float Ks[64][68];
    const int bh = blockIdx.x;
    const int b = bh >> 3;
    const int tid = threadIdx.x;
    const int tk = tid & 63, tg = tid >> 6;

    for (int t = tid; t < 36 * 64; t += 256) {
        int u = t >> 6, d = t & 63;
        float val = 0.f;
        if (u < U_) {
            int l = idx[bh * U_ + u];
            size_t off = ((size_t)bh * L_ + l) * 64 + d;
            val = bf2f(qhi[off]) + bf2f(qlo[off]);
        }
        Qs[d][u] = val;
    }

    const size_t kb = (size_t)bh * L_ * 64;
    const int sr = tid >> 2, sc = (tid & 3) * 16;
    float acc[9];
    const int kt0 = blockIdx.y * 2;
    for (int ki = 0; ki < 2; ++ki) {
        int kt = kt0 + ki;
        if (ki) __syncthreads();
        {
            size_t off = kb + (size_t)(kt * 64 + sr) * 64 + sc;
            uint4 h0 = *(const uint4*)(khi + off);
            uint4 h1 = *(const uint4*)(khi + off + 8);
            uint4 l0 = *(const uint4*)(klo + off);
            uint4 l1 = *(const uint4*)(klo + off + 8);
            unsigned short hv[16], lv[16];
            *(uint4*)hv = h0; *(uint4*)(hv + 8) = h1;
            *(uint4*)lv = l0; *(uint4*)(lv + 8) = l1;
#pragma unroll
            for (int i = 0; i < 16; ++i)
                Ks[sc + i][sr] = bf2f(hv[i]) + bf2f(lv[i]);
        }
        __syncthreads();
#pragma unroll
        for (int j = 0; j < 9; j++) acc[j] = 0.f;
#pragma unroll 4
        for (int d = 0; d < 64; ++d) {
            float kv = Ks[d][tk];
#pragma unroll
            for (int j = 0; j < 9; j++) acc[j] = fmaf(Qs[d][tg + 4 * j], kv, acc[j]);
        }
        const int kcol = kt * 64 + tk;
        const bool msk = (mask[b * L_ + kcol] == 0);
#pragma unroll
        for (int j = 0; j < 9; j++) {
            int u = tg + 4 * j;
            if (u < U_)
                S[((size_t)bh * U_ + u) * 1024 + kcol] = msk ? -INFINITY : acc[j] * 0.125f;
        }
    }
}

// ---------------------------------------------------------------
// softmax over 1024 per row; grid 4480 rows
// ---------------------------------------------------------------
__global__ __launch_bounds__(256) void softmax_rows(float* __restrict__ S)
{
    const size_t base = (size_t)blockIdx.x * 1024;
    const int tid = threadIdx.x;
    __shared__ float redm[4];
    __shared__ float reds[4];
    float4 v = *(const float4*)(S + base + tid * 4);
    float mx = fmaxf(fmaxf(v.x, v.y), fmaxf(v.z, v.w));
#pragma unroll
    for (int off = 32; off; off >>= 1) mx = fmaxf(mx, __shfl_down(mx, off));
    if ((tid & 63) == 0) redm[tid >> 6] = mx;
    __syncthreads();
    mx = fmaxf(fmaxf(redm[0], redm[1]), fmaxf(redm[2], redm[3]));
    float e0 = __expf(v.x - mx), e1 = __expf(v.y - mx);
    float e2 = __expf(v.z - mx), e3 = __expf(v.w - mx);
    float s = e0 + e1 + e2 + e3;
#pragma unroll
    for (int off = 32; off; off >>= 1) s += __shfl_down(s, off);
    if ((tid & 63) == 0) reds[tid >> 6] = s;
    __syncthreads();
    s = reds[0] + reds[1] + reds[2] + reds[3];
    const float inv = 1.0f / s;
    float4 o; o.x = e0 * inv; o.y = e1 * inv; o.z = e2 * inv; o.w = e3 * inv;
    *(float4*)(S + base + tid * 4) = o;
}

// ---------------------------------------------------------------
// ctx partials: grid (128 bh, 8 kc)
// ---------------------------------------------------------------
__global__ __launch_bounds__(256) void ctx_partial(
    const float* __restrict__ S, const float* __restrict__ v,
    float* __restrict__ ctxp)
{
    __shared__ float Vs[128][68];
    __shared__ float Wt[36][128];
    const int bh = blockIdx.x, kc = blockIdx.y;
    const int tid = threadIdx.x;
    const int td = tid & 63, tg = tid >> 6;
    const int lr = tid >> 2, lc0 = (tid & 3) * 16;

    const float* vbase = v + ((size_t)bh * L_ + kc * 128) * 64;
    const float* Sbase = S + (size_t)bh * U_ * 1024 + kc * 128;

#pragma unroll
    for (int hh = 0; hh < 2; ++hh) {
        int row = lr + hh * 64;
        const float* src = vbase + (size_t)row * 64 + lc0;
        *(float4*)&Vs[row][lc0 + 0]  = *(const float4*)(src + 0);
        *(float4*)&Vs[row][lc0 + 4]  = *(const float4*)(src + 4);
        *(float4*)&Vs[row][lc0 + 8]  = *(const float4*)(src + 8);
        *(float4*)&Vs[row][lc0 + 12] = *(const float4*)(src + 12);
    }
    for (int t = tid; t < 36 * 128; t += 256) {
        int u = t >> 7, kk = t & 127;
        Wt[u][kk] = (u < U_) ? Sbase[(size_t)u * 1024 + kk] : 0.f;
    }
    __syncthreads();

    float acc[9];
#pragma unroll
    for (int j = 0; j < 9; j++) acc[j] = 0.f;
#pragma unroll 2
    for (int kk = 0; kk < 128; ++kk) {
        float vv = Vs[kk][td];
#pragma unroll
        for (int j = 0; j < 9; j++) acc[j] = fmaf(Wt[tg + 4 * j][kk], vv, acc[j]);
    }
#pragma unroll
    for (int j = 0; j < 9; j++) {
        int u = tg + 4 * j;
        if (u < U_)
            ctxp[((size_t)(kc * 128 + bh) * 36 + u) * 64 + td] = acc[j];
    }
}

// ---------------------------------------------------------------
// ctxd[bh][u][d] = sum_kc ctxp - vmean[bh][d] ; grid 1120 x 256
// ---------------------------------------------------------------
__global__ __launch_bounds__(256) void ctx_reduce_diff(
    const float* __restrict__ ctxp, const float* __restrict__ vmean,
    float* __restrict__ ctxd)
{
    const int i = blockIdx.x * 256 + threadIdx.x;   // 128*35*64 = 286720
    const int d = i & 63;
    const int rest = i >> 6;
    const int u = rest % U_;
    const int bh = rest / U_;
    float s = 0.f;
#pragma unroll
    for (int kc = 0; kc < 8; ++kc)
        s += ctxp[((size_t)(kc * 128 + bh) * 36 + u) * 64 + d];
    ctxd[i] = s - vmean[(size_t)bh * 64 + d];
}

// ---------------------------------------------------------------
// obase[b][n] = dot(xbar[b], Wo[n]) + bo[n] ; grid 128 (16 b x 8 nchunk)
// ---------------------------------------------------------------
__global__ __launch_bounds__(256) void vmean_proj(
    const float* __restrict__ vmean, const float* __restrict__ Wo,
    const float* __restrict__ bo, float* __restrict__ obase)
{
    const int b = blockIdx.x >> 3, n0 = (blockIdx.x & 7) * 64;
    const int tid = threadIdx.x;
    __shared__ float xbar[512];
    __shared__ float psum[64][5];
    for (int i = tid; i < 512; i += 256)
        xbar[i] = vmean[(size_t)(b * 8 + (i >> 6)) * 64 + (i & 63)];
    __syncthreads();
    const int n = n0 + (tid >> 2), fq = (tid & 3) * 128;
    float s = 0.f;
    for (int f = 0; f < 128; f += 4) {
        float4 w = *(const float4*)(Wo + (size_t)n * 512 + fq + f);
        s += xbar[fq + f] * w.x + xbar[fq + f + 1] * w.y +
             xbar[fq + f + 2] * w.z + xbar[fq + f + 3] * w.w;
    }
    psum[tid >> 2][tid & 3] = s;
    __syncthreads();
    if (tid < 64)
        obase[(size_t)b * 512 + n0 + tid] =
            psum[tid][0] + psum[tid][1] + psum[tid][2] + psum[tid][3] + bo[n0 + tid];
}

// ---------------------------------------------------------------
// out[b][l][:] = obase[b][:] ; grid 8192 x 256 (float4)
// ---------------------------------------------------------------
__global__ void broadcast_out(const float* __restrict__ obase, float* __restrict__ out)
{
    const size_t e = ((size_t)blockIdx.x * 256 + threadIdx.x) * 4;
    const int n = (int)(e & 511);
    const int b = (int)(e >> 19);
    *(float4*)(out + e) = *(const float4*)(obase + (b << 9) + n);
}

// ---------------------------------------------------------------
// out[b][l_u][n] += ctxd[bh][u] . Wo[n][h*64..]
// grid (128 bh, 4 col-chunks) x 128 threads; one column n per thread.
// ---------------------------------------------------------------
__global__ __launch_bounds__(128) void delta_out(
    const float* __restrict__ ctxd, const int* __restrict__ idx,
    const float* __restrict__ Wo, float* __restrict__ out)
{
    const int bh = blockIdx.x, b = bh >> 3, h = bh & 7;
    const int tid = threadIdx.x;
    const int n = blockIdx.y * 128 + tid;
    __shared__ float sd[U_][64];
    __shared__ int ls[U_];
    if (tid < U_) ls[tid] = idx[bh * U_ + tid];
    for (int t = tid; t < U_ * 64; t += 128)
        sd[t >> 6][t & 63] = ctxd[(size_t)bh * U_ * 64 + t];

    float4 w[16];
    const float* wp = Wo + (size_t)n * 512 + h * 64;
#pragma unroll
    for (int jc = 0; jc < 16; ++jc) w[jc] = *(const float4*)(wp + jc * 4);
    __syncthreads();

    for (int u = 0; u < U_; ++u) {
        float acc = 0.f;
#pragma unroll
        for (int jc = 0; jc < 16; ++jc) {
            float4 dv = *(const float4*)&sd[u][jc * 4];
            acc = fmaf(dv.w, w[jc].w, fmaf(dv.z, w[jc].z,
                  fmaf(dv.y, w[jc].y, fmaf(dv.x, w[jc].x, acc))));
        }
        atomicAdd(out + ((size_t)b * L_ + ls[u]) * 512 + n, acc);
    }
}

// ---------------------------------------------------------------
extern "C" void kernel_launch(void* const* d_in, const int* in_sizes, int n_in,
                              void* d_out, int out_size, void* d_ws, size_t ws_size,
                              hipStream_t stream)
{
    (void)in_sizes; (void)n_in; (void)out_size; (void)ws_size;
    const float* query = (const float*)d_in[0];
    const float* key   = (const float*)d_in[1];
    const float* value = (const float*)d_in[2];
    const int*   mask  = (const int*)d_in[3];
    const float* Wq = (const float*)d_in[4];
    const float* bq = (const float*)d_in[5];
    const float* Wk = (const float*)d_in[6];
    const float* bk = (const float*)d_in[7];
    const float* Wv = (const float*)d_in[8];
    const float* bvp = (const float*)d_in[9];
    const float* Wo = (const float*)d_in[10];
    const float* bo = (const float*)d_in[11];
    float* out = (float*)d_out;

    float* ws = (float*)d_ws;
    float* v      = ws + OFF_V;
    unsigned short* q_hi = (unsigned short*)(ws + OFF_QHI);
    unsigned short* q_lo = (unsigned short*)(ws + OFF_QLO);
    unsigned short* k_hi = (unsigned short*)(ws + OFF_KHI);
    unsigned short* k_lo = (unsigned short*)(ws + OFF_KLO);
    float* ctxp   = ws + OFF_CTXP;
    float* S      = ws + OFF_S;
    float* Marr   = ws + OFF_M;
    float* kmean  = ws + OFF_KMEAN;
    float* vmean  = ws + OFF_VMEAN;
    float* ctxd   = ws + OFF_CTXD;
    int*   idx    = (int*)(ws + OFF_IDX);
    float* obase  = ws + OFF_OBASE;
    unsigned short* wqh = (unsigned short*)(ws + OFF_WQH);
    unsigned short* wql = (unsigned short*)(ws + OFF_WQL);
    unsigned short* wkh = (unsigned short*)(ws + OFF_WKH);
    unsigned short* wkl = (unsigned short*)(ws + OFF_WKL);
    unsigned short* wvh = (unsigned short*)(ws + OFF_WVH);
    unsigned short* wvl = (unsigned short*)(ws + OFF_WVL);

    // weight splits (fused)
    split_w3<<<3072, 256, 0, stream>>>(Wq, Wk, Wv, wqh, wql, wkh, wkl, wvh, wvl);

    // projections: single fused dispatch (z = q/k/v), async B staging,
    // cvt_pk A-conversion, LDS-staged coalesced epilogue.
    gemm_qkv<<<dim3(128, 4, 3), 256, 0, stream>>>(
        query, key, value,
        wqh, wql, wkh, wkl, wvh, wvl,
        bq, bk, bvp,
        v, q_hi, q_lo, k_hi, k_lo);

    // per-(b,h) means (fused) + base output row
    means_fused<<<256, 256, 0, stream>>>(k_hi, k_lo, v, kmean, vmean);
    vmean_proj<<<128, 256, 0, stream>>>(vmean, Wo, bo, obase);

    // sparsity measure M (MFMA, XCD-swizzled, hoisted-Q, 64-row tiles)
    qk_rowmax_mfma<<<dim3(128, 16), 256, 0, stream>>>(q_hi, q_lo, k_hi, k_lo, kmean, Marr);
    topk35<<<128, 256, 0, stream>>>(Marr, idx);

    // reduced attention (K-split for parallelism)
    scores_red<<<dim3(128, 8), 256, 0, stream>>>(q_hi, q_lo, k_hi, k_lo, idx, mask, S);
    softmax_rows<<<B_ * H_ * U_, 256, 0, stream>>>(S);
    ctx_partial<<<dim3(128, 8), 256, 0, stream>>>(S, v, ctxp);   // ctxp aliases q_hi (dead)
    ctx_reduce_diff<<<1120, 256, 0, stream>>>(ctxp, vmean, ctxd);

    // output = broadcast base row + sparse delta (replaces full Wo GEMM)
    broadcast_out<<<8192, 256, 0, stream>>>(obase, out);
    delta_out<<<dim3(128, 4), 128, 0, stream>>>(ctxd, idx, Wo, out);
}

// Round 4
// 435.364 us; speedup vs baseline: 1.0665x; 1.0324x over previous
//
#include <hip/hip_runtime.h>
#include <math.h>

#define B_ 16
#define L_ 1024
#define H_ 8
#define U_ 35

typedef float f32x4 __attribute__((ext_vector_type(4)));
typedef short bf16x8 __attribute__((ext_vector_type(8)));

__device__ __forceinline__ unsigned short f2bf(float x) {
    unsigned int u = __float_as_uint(x);
    u += 0x7FFFu + ((u >> 16) & 1u);      // round-to-nearest-even
    return (unsigned short)(u >> 16);
}
__device__ __forceinline__ float bf2f(unsigned short b) {
    return __uint_as_float(((unsigned int)b) << 16);
}

// packed f32x2 -> bf16x2 in ONE VALU op (no builtin on gfx950; T12 recipe).
__device__ __forceinline__ unsigned int cvt_pk_bf16(float a, float b) {
    unsigned int r;
    asm("v_cvt_pk_bf16_f32 %0, %1, %2" : "=v"(r) : "v"(a), "v"(b));
    return r;
}

// async global->LDS, 16B per lane
__device__ __forceinline__ void gl_lds16(const void* g, void* l) {
    __builtin_amdgcn_global_load_lds(
        (const __attribute__((address_space(1))) unsigned int*)g,
        (__attribute__((address_space(3))) unsigned int*)l, 16, 0, 0);
}

#define MFMA(a, b, c) __builtin_amdgcn_mfma_f32_16x16x32_bf16((a), (b), (c), 0, 0, 0)

// ---------------- workspace layout (float-element offsets) ----------------
#define OFF_V      ((size_t)0)           // 8388608 f
#define OFF_QHI    ((size_t)8388608)     // 4194304
#define OFF_QLO    ((size_t)12582912)    // 4194304
#define OFF_CTXP   OFF_QHI               // ctx partials alias q_hi (dead after scores)
#define OFF_KHI    ((size_t)16777216)    // 4194304
#define OFF_KLO    ((size_t)20971520)    // 4194304
#define OFF_S      ((size_t)25165824)    // 4587520
#define OFF_WQH    OFF_S                 // W splits alias S (dead before scores)
#define OFF_WQL    ((size_t)(OFF_S + 131072))
#define OFF_WKH    ((size_t)(OFF_S + 262144))
#define OFF_WKL    ((size_t)(OFF_S + 393216))
#define OFF_WVH    ((size_t)(OFF_S + 524288))
#define OFF_WVL    ((size_t)(OFF_S + 655360))
#define OFF_M      ((size_t)29753344)    // 131072
#define OFF_KMEAN  ((size_t)29884416)    // 8192
#define OFF_VMEAN  ((size_t)29892608)    // 8192
#define OFF_CTXD   ((size_t)29900800)    // 286720 (ctx - vmean diffs)
#define OFF_IDX    ((size_t)30187520)    // 4480
#define OFF_OBASE  ((size_t)30192000)    // 8192 (per-b base output row)
// end ~30.2M f = ~121 MB

// ---------------------------------------------------------------
// split Wq/Wk/Wv fp32 -> hi/lo bf16; grid 3072 x 256
// ---------------------------------------------------------------
__global__ __launch_bounds__(256) void split_w3(
    const float* __restrict__ Wq, const float* __restrict__ Wk,
    const float* __restrict__ Wv,
    unsigned short* __restrict__ wqh, unsigned short* __restrict__ wql,
    unsigned short* __restrict__ wkh, unsigned short* __restrict__ wkl,
    unsigned short* __restrict__ wvh, unsigned short* __restrict__ wvl)
{
    const int w = blockIdx.x >> 10;
    const int i = (blockIdx.x & 1023) * 256 + threadIdx.x;
    const float* W = (w == 0) ? Wq : (w == 1) ? Wk : Wv;
    unsigned short* hi = (w == 0) ? wqh : (w == 1) ? wkh : wvh;
    unsigned short* lo = (w == 0) ? wql : (w == 1) ? wkl : wvl;
    float x = W[i];
    unsigned short h = f2bf(x);
    hi[i] = h;
    lo[i] = f2bf(x - bf2f(h));
}

// ---------------------------------------------------------------
// Fused bf16x2 MFMA GEMM for all three projections (z = q/k/v).
// R4 changes (MFMA 24 / VALU 17 / HBM 15% all low -> 2-phase stage
// latency is the critical path):
//  - T14 async-split for A: next-tile float4 loads issued right after
//    barrier2, in flight under the whole MFMA phase, consumed
//    (convert+ds_write) after the next barrier.
//  - B-read 4-way-deconflict: per-lane swizzled global source (16B-block
//    XOR within row) + XOR'd ds_read address. All 9.4M conflict cycles
//    were the linear 64B-row B tile (8-way on ds_read_b128).
// Math bit-identical -> absmax must not move.
// ---------------------------------------------------------------
__global__ __launch_bounds__(256) void gemm_qkv(
    const float* __restrict__ Aq, const float* __restrict__ Ak,
    const float* __restrict__ Av,
    const unsigned short* __restrict__ wqh, const unsigned short* __restrict__ wql,
    const unsigned short* __restrict__ wkh, const unsigned short* __restrict__ wkl,
    const unsigned short* __restrict__ wvh, const unsigned short* __restrict__ wvl,
    const float* __restrict__ bqp, const float* __restrict__ bkp,
    const float* __restrict__ bvp,
    float* __restrict__ vout,
    unsigned short* __restrict__ qhi_o, unsigned short* __restrict__ qlo_o,
    unsigned short* __restrict__ khi_o, unsigned short* __restrict__ klo_o)
{
    // one raw LDS pool, aliased: staging (36864 B) then epilogue Cf (34816 B)
    __shared__ __align__(16) unsigned char smem[36864];
    unsigned short (*Ah)[40] = (unsigned short (*)[40])(smem);            // 10240 B
    unsigned short (*Al)[40] = (unsigned short (*)[40])(smem + 10240);    // 10240 B
    unsigned char* Bh = smem + 20480;                                     //  8192 B [128][32] swz
    unsigned char* Bl = smem + 28672;                                     //  8192 B
    float (*Cf)[68] = (float (*)[68])(smem);                              // 34816 B

    const int z = blockIdx.z;
    const float* A = (z == 0) ? Aq : (z == 1) ? Ak : Av;
    const unsigned short* Whi = (z == 0) ? wqh : (z == 1) ? wkh : wvh;
    const unsigned short* Wlo = (z == 0) ? wql : (z == 1) ? wkl : wvl;
    const float* bias = (z == 0) ? bqp : (z == 1) ? bkp : bvp;
    unsigned short* ohi = (z == 0) ? qhi_o : (z == 1) ? khi_o : nullptr;
    unsigned short* olo = (z == 0) ? qlo_o : (z == 1) ? klo_o : nullptr;

    const int tid = threadIdx.x, lane = tid & 63, wave = tid >> 6;
    const int m0 = blockIdx.x * 128, n0 = blockIdx.y * 128;
    const int wm = (wave >> 1) * 64, wn = (wave & 1) * 64;

    f32x4 zero4 = {0.f, 0.f, 0.f, 0.f};
    f32x4 acc[4][4];
#pragma unroll
    for (int i = 0; i < 4; i++)
#pragma unroll
        for (int j = 0; j < 4; j++) acc[i][j] = zero4;

    const int ar = tid >> 3, ac = (tid & 7) * 4;
    const int kc = (lane >> 4) * 8;
    const int fr = lane & 15;
    // B staging: issue i covers rows i*64..i*64+63 of the [128][32] tile.
    // Per-lane SOURCE col swizzled so linear LDS dest == XOR-swizzled tile.
    const int btr = tid >> 2;                               // row within issue
    const int btc = ((tid & 3) ^ ((tid >> 2) & 3)) * 8;     // swizzled src col
    const int bldsoff = tid * 16;                           // linear dest

    // T14: prologue A loads (tile 0)
    float4 areg[4];
#pragma unroll
    for (int p = 0; p < 4; ++p)
        areg[p] = *(const float4*)(A + (size_t)(m0 + ar + p * 32) * 512 + ac);

    for (int k0 = 0; k0 < 512; k0 += 32) {
        if (k0) __syncthreads();           // barrier1: prev readers done
        // --- B: async global->LDS (swizzled source, linear dest)
#pragma unroll
        for (int i = 0; i < 2; ++i) {
            size_t gb = (size_t)(n0 + i * 64 + btr) * 512 + k0 + btc;
            gl_lds16(Whi + gb, Bh + i * 4096 + bldsoff);
            gl_lds16(Wlo + gb, Bl + i * 4096 + bldsoff);
        }
        // --- A: convert prefetched regs (no fresh load latency here)
#pragma unroll
        for (int p = 0; p < 4; ++p) {
            float4 a4 = areg[p];
            unsigned int h01 = cvt_pk_bf16(a4.x, a4.y);
            unsigned int h23 = cvt_pk_bf16(a4.z, a4.w);
            float r0 = a4.x - __uint_as_float(h01 << 16);
            float r1 = a4.y - __uint_as_float(h01 & 0xFFFF0000u);
            float r2 = a4.z - __uint_as_float(h23 << 16);
            float r3 = a4.w - __uint_as_float(h23 & 0xFFFF0000u);
            unsigned int l01 = cvt_pk_bf16(r0, r1);
            unsigned int l23 = cvt_pk_bf16(r2, r3);
            uint2 hh; hh.x = h01; hh.y = h23;
            uint2 ll; ll.x = l01; ll.y = l23;
            *(uint2*)&Ah[ar + p * 32][ac] = hh;
            *(uint2*)&Al[ar + p * 32][ac] = ll;
        }
        __syncthreads();   // barrier2: drains B vmcnt + A ds_writes
        // T14: issue NEXT tile's A loads — fly under the MFMA phase,
        // consumed after the next barrier1.
        if (k0 + 32 < 512) {
#pragma unroll
            for (int p = 0; p < 4; ++p)
                areg[p] = *(const float4*)(A + (size_t)(m0 + ar + p * 32) * 512 + k0 + 32 + ac);
        }

        bf16x8 ah[4], al[4];
#pragma unroll
        for (int mi = 0; mi < 4; ++mi) {
            int row = wm + mi * 16 + fr;
            ah[mi] = *(bf16x8*)&Ah[row][kc];
            al[mi] = *(bf16x8*)&Al[row][kc];
        }
#pragma unroll
        for (int ni = 0; ni < 4; ++ni) {
            int rn = wn + ni * 16 + fr;
            int bb = rn * 64 + ((kc * 2) ^ ((rn & 3) << 4));   // swizzled read
            bf16x8 bh8 = *(bf16x8*)(Bh + bb);
            bf16x8 bl8 = *(bf16x8*)(Bl + bb);
#pragma unroll
            for (int mi = 0; mi < 4; ++mi) {
                acc[mi][ni] = MFMA(ah[mi], bh8, acc[mi][ni]);
                acc[mi][ni] = MFMA(ah[mi], bl8, acc[mi][ni]);
                acc[mi][ni] = MFMA(al[mi], bh8, acc[mi][ni]);
            }
        }
    }

    // ---------------- epilogue: LDS-staged, coalesced stores ----------------
    const int col = lane & 15, rq = (lane >> 4) * 4;
    const int b_ = m0 >> 10;       // 128-row tile lies within one b
    const int l0 = m0 & 1023;

#pragma unroll
    for (int half = 0; half < 2; ++half) {
        __syncthreads();           // staging buffers dead / previous half stored
        if ((wave & 1) == half) {  // waves holding cols [half*64, half*64+64)
#pragma unroll
            for (int ni = 0; ni < 4; ++ni) {
                float bn = bias[n0 + half * 64 + ni * 16 + col];
#pragma unroll
                for (int mi = 0; mi < 4; ++mi)
#pragma unroll
                    for (int r = 0; r < 4; ++r)
                        Cf[wm + mi * 16 + rq + r][ni * 16 + col] = acc[mi][ni][r] + bn;
            }
        }
        __syncthreads();
        const int h_ = (n0 >> 6) + half;
        const size_t plane = ((size_t)(b_ * H_ + h_) * L_ + l0) * 64;
        if (z == 2) {
            const int r = tid >> 1, d0 = (tid & 1) * 32;
#pragma unroll
            for (int j = 0; j < 8; ++j) {
                float4 val = *(const float4*)&Cf[r][d0 + j * 4];
                *(float4*)(vout + plane + (size_t)r * 64 + d0 + j * 4) = val;
            }
        } else {
            const int r = tid >> 1, d0 = (tid & 1) * 32;
#pragma unroll
            for (int c = 0; c < 4; ++c) {
                float x[8];
#pragma unroll
                for (int j = 0; j < 8; ++j) x[j] = Cf[r][d0 + c * 8 + j];
                unsigned int h01 = cvt_pk_bf16(x[0], x[1]);
                unsigned int h23 = cvt_pk_bf16(x[2], x[3]);
                unsigned int h45 = cvt_pk_bf16(x[4], x[5]);
                unsigned int h67 = cvt_pk_bf16(x[6], x[7]);
                float r0 = x[0] - __uint_as_float(h01 << 16);
                float r1 = x[1] - __uint_as_float(h01 & 0xFFFF0000u);
                float r2 = x[2] - __uint_as_float(h23 << 16);
                float r3 = x[3] - __uint_as_float(h23 & 0xFFFF0000u);
                float r4 = x[4] - __uint_as_float(h45 << 16);
                float r5 = x[5] - __uint_as_float(h45 & 0xFFFF0000u);
                float r6 = x[6] - __uint_as_float(h67 << 16);
                float r7 = x[7] - __uint_as_float(h67 & 0xFFFF0000u);
                uint4 ph; ph.x = h01; ph.y = h23; ph.z = h45; ph.w = h67;
                uint4 pl;
                pl.x = cvt_pk_bf16(r0, r1);
                pl.y = cvt_pk_bf16(r2, r3);
                pl.z = cvt_pk_bf16(r4, r5);
                pl.w = cvt_pk_bf16(r6, r7);
                *(uint4*)(ohi + plane + (size_t)r * 64 + d0 + c * 8) = ph;
                *(uint4*)(olo + plane + (size_t)r * 64 + d0 + c * 8) = pl;
            }
        }
    }
}

// ---------------------------------------------------------------
// fused means: blocks 0..127 -> kmean (from k hi/lo), 128..255 -> vmean (fp32)
// ---------------------------------------------------------------
__global__ __launch_bounds__(256) void means_fused(
    const unsigned short* __restrict__ khi, const unsigned short* __restrict__ klo,
    const float* __restrict__ v, float* __restrict__ kmean, float* __restrict__ vmean)
{
    const int which = blockIdx.x >> 7;
    const int bh = blockIdx.x & 127;
    const int d = threadIdx.x & 63, g = threadIdx.x >> 6;
    __shared__ float red[4][64];
    float s = 0.f;
    if (which == 0) {
        size_t base = ((size_t)bh * L_ + g * 256) * 64 + d;
#pragma unroll 8
        for (int l = 0; l < 256; l++) {
            size_t o = base + (size_t)l * 64;
            s += bf2f(khi[o]) + bf2f(klo[o]);
        }
    } else {
        const float* p = v + ((size_t)bh * L_ + g * 256) * 64 + d;
#pragma unroll 8
        for (int l = 0; l < 256; l++) s += p[(size_t)l * 64];
    }
    red[g][d] = s;
    __syncthreads();
    if (threadIdx.x < 64) {
        const int dd = threadIdx.x;
        float m = (red[0][dd] + red[1][dd] + red[2][dd] + red[3][dd]) * (1.0f / 1024.0f);
        (which == 0 ? kmean : vmean)[(size_t)bh * 64 + dd] = m;
    }
}

// ---------------------------------------------------------------
// M[l] = max_k(q_l . k_k) - q_l . kmean via bf16x2 MFMA
// grid (128 bh, 16 qt): XCD-local K reuse (id%8 = bh%8 pins the XCD).
// R4 rewrite: K staged via global_load_lds (width 16) into a
// DOUBLE-BUFFERED XOR-swizzled [64 rows][128B] tile; ONE barrier per
// K-tile (stage(t+1) issued before MFMA(t), drained by the end-of-iter
// barrier -> staging hidden under MFMA). Linear layout would be a
// 16-way ds_read_b128 conflict; byte ^= (row&7)<<4 makes it ~2-way.
// Swizzle applied via per-lane global source col (m173) — both sides.
// ---------------------------------------------------------------
__global__ __launch_bounds__(256) void qk_rowmax_mfma(
    const unsigned short* __restrict__ qhi, const unsigned short* __restrict__ qlo,
    const unsigned short* __restrict__ khi, const unsigned short* __restrict__ klo,
    const float* __restrict__ kmean, float* __restrict__ Mout)
{
    __shared__ unsigned short Qh[64][72], Ql[64][72];      // 18432 B
    __shared__ __align__(16) unsigned char Kp[2][2][8192]; // [buf][hi/lo], swz
    __shared__ float Mred[64][4];
    __shared__ float km[64];
    const int bh = blockIdx.x, q0 = blockIdx.y * 64;
    const int tid = threadIdx.x, lane = tid & 63, wave = tid >> 6;

    if (tid < 64) km[tid] = kmean[bh * 64 + tid];
    {
        int r = tid >> 2, c = (tid & 3) * 16;
        size_t off = ((size_t)bh * L_ + q0 + r) * 64 + c;
        *(uint4*)&Qh[r][c]     = *(const uint4*)(qhi + off);
        *(uint4*)&Qh[r][c + 8] = *(const uint4*)(qhi + off + 8);
        *(uint4*)&Ql[r][c]     = *(const uint4*)(qlo + off);
        *(uint4*)&Ql[r][c + 8] = *(const uint4*)(qlo + off + 8);
    }

    const size_t kb = (size_t)bh * L_ * 64;
    // K staging geometry: 2 issues of 16B/lane cover 64 rows x 128B.
    // Linear dest byte = tid*16 (+4096 for issue 1); row = tid>>3.
    // Swizzled content via source col: block16 = (tid&7) ^ ((tid>>3)&7).
    const int srow = tid >> 3;
    const int scol = ((tid & 7) ^ ((tid >> 3) & 7)) * 8;
    const int sdst = tid * 16;

    // stage K tile 0 into buf 0
    {
        size_t g0 = kb + (size_t)(srow) * 64 + scol;
        size_t g1 = kb + (size_t)(32 + srow) * 64 + scol;
        gl_lds16(khi + g0, &Kp[0][0][sdst]);
        gl_lds16(khi + g1, &Kp[0][0][4096 + sdst]);
        gl_lds16(klo + g0, &Kp[0][1][sdst]);
        gl_lds16(klo + g1, &Kp[0][1][4096 + sdst]);
    }
    __syncthreads();   // Q/km staged + K tile 0 complete (vmcnt+lgkm drain)

    const int fr = lane & 15;
    f32x4 zero4 = {0.f, 0.f, 0.f, 0.f};

    // hoist Q fragments into registers — invariant across the K loop
    bf16x8 qah[2][4], qal[2][4];
#pragma unroll
    for (int ks = 0; ks < 2; ++ks) {
        int kcol = ks * 32 + (lane >> 4) * 8;
#pragma unroll
        for (int mi = 0; mi < 4; ++mi) {
            qah[ks][mi] = *(bf16x8*)&Qh[mi * 16 + fr][kcol];
            qal[ks][mi] = *(bf16x8*)&Ql[mi * 16 + fr][kcol];
        }
    }

    float rmax[4][4];
#pragma unroll
    for (int mi = 0; mi < 4; ++mi)
#pragma unroll
        for (int r = 0; r < 4; ++r) rmax[mi][r] = -INFINITY;

    const int krow = wave * 16 + fr;
    const int kbase = krow * 128;
    const int kxor = (krow & 7) << 4;

    for (int kt = 0; kt < 16; ++kt) {
        const int cur = kt & 1;
        if (kt < 15) {   // stage next tile into the other buffer (async;
                         // in flight under the MFMAs, drained at the barrier)
            const int nb = cur ^ 1;
            size_t g0 = kb + (size_t)((kt + 1) * 64 + srow) * 64 + scol;
            size_t g1 = g0 + (size_t)32 * 64;
            gl_lds16(khi + g0, &Kp[nb][0][sdst]);
            gl_lds16(khi + g1, &Kp[nb][0][4096 + sdst]);
            gl_lds16(klo + g0, &Kp[nb][1][sdst]);
            gl_lds16(klo + g1, &Kp[nb][1][4096 + sdst]);
        }

        f32x4 acc[4];
#pragma unroll
        for (int mi = 0; mi < 4; ++mi) acc[mi] = zero4;

#pragma unroll
        for (int ks = 0; ks < 2; ++ks) {
            int byte = kbase + (((ks * 32 + (lane >> 4) * 8) * 2) ^ kxor);
            bf16x8 bh8 = *(bf16x8*)&Kp[cur][0][byte];
            bf16x8 bl8 = *(bf16x8*)&Kp[cur][1][byte];
#pragma unroll
            for (int mi = 0; mi < 4; ++mi) {
                acc[mi] = MFMA(qah[ks][mi], bh8, acc[mi]);
                acc[mi] = MFMA(qah[ks][mi], bl8, acc[mi]);
                acc[mi] = MFMA(qal[ks][mi], bh8, acc[mi]);
            }
        }
#pragma unroll
        for (int mi = 0; mi < 4; ++mi)
#pragma unroll
            for (int r = 0; r < 4; ++r)
                rmax[mi][r] = fmaxf(rmax[mi][r], acc[mi][r]);

        __syncthreads();   // next-tile loads drained; buffers synced
    }

    // reduce over the 16 k-columns held across lanes of each 16-group
#pragma unroll
    for (int mi = 0; mi < 4; ++mi)
#pragma unroll
        for (int r = 0; r < 4; ++r) {
            float v = rmax[mi][r];
            v = fmaxf(v, __shfl_xor(v, 1));
            v = fmaxf(v, __shfl_xor(v, 2));
            v = fmaxf(v, __shfl_xor(v, 4));
            v = fmaxf(v, __shfl_xor(v, 8));
            rmax[mi][r] = v;
        }
    if ((lane & 15) == 0) {
        int quad = lane >> 4;
#pragma unroll
        for (int mi = 0; mi < 4; ++mi)
#pragma unroll
            for (int r = 0; r < 4; ++r)
                Mred[mi * 16 + quad * 4 + r][wave] = rmax[mi][r];
    }
    __syncthreads();
    if (tid < 64) {
        float mx = fmaxf(fmaxf(Mred[tid][0], Mred[tid][1]),
                         fmaxf(Mred[tid][2], Mred[tid][3]));
        float dot = 0.f;
#pragma unroll 4
        for (int d = 0; d < 64; ++d)
            dot = fmaf(bf2f(Qh[tid][d]) + bf2f(Ql[tid][d]), km[d], dot);
        Mout[(size_t)bh * L_ + q0 + tid] = mx - dot;
    }
}

// ---------------------------------------------------------------
// top-35 of M[1024] per (b,h)
// ---------------------------------------------------------------
__global__ __launch_bounds__(256) void topk35(
    const float* __restrict__ Min, int* __restrict__ idx_out)
{
    const int bh = blockIdx.x;
    const int tid = threadIdx.x;
    __shared__ float vals[1024];
    __shared__ float wv[4];
    __shared__ int wi[4];
    for (int i = tid; i < 1024; i += 256) vals[i] = Min[(size_t)bh * 1024 + i];
    __syncthreads();
    for (int it = 0; it < U_; ++it) {
        float bv = -INFINITY; int bi = 1 << 30;
        for (int i = tid; i < 1024; i += 256) {
            float x = vals[i];
            if (x > bv) { bv = x; bi = i; }
        }
#pragma unroll
        for (int off = 32; off; off >>= 1) {
            float ov = __shfl_down(bv, off);
            int   oi = __shfl_down(bi, off);
            if (ov > bv || (ov == bv && oi < bi)) { bv = ov; bi = oi; }
        }
        if ((tid & 63) == 0) { wv[tid >> 6] = bv; wi[tid >> 6] = bi; }
        __syncthreads();
        if (tid == 0) {
#pragma unroll
            for (int w = 1; w < 4; ++w) {
                if (wv[w] > bv || (wv[w] == bv && wi[w] < bi)) { bv = wv[w]; bi = wi[w]; }
            }
            idx_out[bh * U_ + it] = bi;
            vals[bi] = -INFINITY;
        }
        __syncthreads();
    }
}

// ---------------------------------------------------------------
// S[u][k] = (q[idx_u] . k_k)/8 masked; grid (128 bh, 8 key-chunks)
// ---------------------------------------------------------------
__global__ __launch_bounds__(256) void scores_red(
    const unsigned short* __restrict__ qhi, const unsigned short* __restrict__ qlo,
    const unsigned short* __restrict__ khi, const unsigned short* __restrict__ klo,
    const int* __restrict__ idx, const int* __restrict__ mask,
    float* __restrict__ S)
{
    __shared__ float Qs[64][36];
    __shared__ float Ks[64][68];
    const int bh = blockIdx.x;
    const int b = bh >> 3;
    const int tid = threadIdx.x;
    const int tk = tid & 63, tg = tid >> 6;

    for (int t = tid; t < 36 * 64; t += 256) {
        int u = t >> 6, d = t & 63;
        float val = 0.f;
        if (u < U_) {
            int l = idx[bh * U_ + u];
            size_t off = ((size_t)bh * L_ + l) * 64 + d;
            val = bf2f(qhi[off]) + bf2f(qlo[off]);
        }
        Qs[d][u] = val;
    }

    const size_t kb = (size_t)bh * L_ * 64;
    const int sr = tid >> 2, sc = (tid & 3) * 16;
    float acc[9];
    const int kt0 = blockIdx.y * 2;
    for (int ki = 0; ki < 2; ++ki) {
        int kt = kt0 + ki;
        if (ki) __syncthreads();
        {
            size_t off = kb + (size_t)(kt * 64 + sr) * 64 + sc;
            uint4 h0 = *(const uint4*)(khi + off);
            uint4 h1 = *(const uint4*)(khi + off + 8);
            uint4 l0 = *(const uint4*)(klo + off);
            uint4 l1 = *(const uint4*)(klo + off + 8);
            unsigned short hv[16], lv[16];
            *(uint4*)hv = h0; *(uint4*)(hv + 8) = h1;
            *(uint4*)lv = l0; *(uint4*)(lv + 8) = l1;
#pragma unroll
            for (int i = 0; i < 16; ++i)
                Ks[sc + i][sr] = bf2f(hv[i]) + bf2f(lv[i]);
        }
        __syncthreads();
#pragma unroll
        for (int j = 0; j < 9; j++) acc[j] = 0.f;
#pragma unroll 4
        for (int d = 0; d < 64; ++d) {
            float kv = Ks[d][tk];
#pragma unroll
            for (int j = 0; j < 9; j++) acc[j] = fmaf(Qs[d][tg + 4 * j], kv, acc[j]);
        }
        const int kcol = kt * 64 + tk;
        const bool msk = (mask[b * L_ + kcol] == 0);
#pragma unroll
        for (int j = 0; j < 9; j++) {
            int u = tg + 4 * j;
            if (u < U_)
                S[((size_t)bh * U_ + u) * 1024 + kcol] = msk ? -INFINITY : acc[j] * 0.125f;
        }
    }
}

// ---------------------------------------------------------------
// softmax over 1024 per row; grid 4480 rows
// ---------------------------------------------------------------
__global__ __launch_bounds__(256) void softmax_rows(float* __restrict__ S)
{
    const size_t base = (size_t)blockIdx.x * 1024;
    const int tid = threadIdx.x;
    __shared__ float redm[4];
    __shared__ float reds[4];
    float4 v = *(const float4*)(S + base + tid * 4);
    float mx = fmaxf(fmaxf(v.x, v.y), fmaxf(v.z, v.w));
#pragma unroll
    for (int off = 32; off; off >>= 1) mx = fmaxf(mx, __shfl_down(mx, off));
    if ((tid & 63) == 0) redm[tid >> 6] = mx;
    __syncthreads();
    mx = fmaxf(fmaxf(redm[0], redm[1]), fmaxf(redm[2], redm[3]));
    float e0 = __expf(v.x - mx), e1 = __expf(v.y - mx);
    float e2 = __expf(v.z - mx), e3 = __expf(v.w - mx);
    float s = e0 + e1 + e2 + e3;
#pragma unroll
    for (int off = 32; off; off >>= 1) s += __shfl_down(s, off);
    if ((tid & 63) == 0) reds[tid >> 6] = s;
    __syncthreads();
    s = reds[0] + reds[1] + reds[2] + reds[3];
    const float inv = 1.0f / s;
    float4 o; o.x = e0 * inv; o.y = e1 * inv; o.z = e2 * inv; o.w = e3 * inv;
    *(float4*)(S + base + tid * 4) = o;
}

// ---------------------------------------------------------------
// ctx partials: grid (128 bh, 8 kc)
// ---------------------------------------------------------------
__global__ __launch_bounds__(256) void ctx_partial(
    const float* __restrict__ S, const float* __restrict__ v,
    float* __restrict__ ctxp)
{
    __shared__ float Vs[128][68];
    __shared__ float Wt[36][128];
    const int bh = blockIdx.x, kc = blockIdx.y;
    const int tid = threadIdx.x;
    const int td = tid & 63, tg = tid >> 6;
    const int lr = tid >> 2, lc0 = (tid & 3) * 16;

    const float* vbase = v + ((size_t)bh * L_ + kc * 128) * 64;
    const float* Sbase = S + (size_t)bh * U_ * 1024 + kc * 128;

#pragma unroll
    for (int hh = 0; hh < 2; ++hh) {
        int row = lr + hh * 64;
        const float* src = vbase + (size_t)row * 64 + lc0;
        *(float4*)&Vs[row][lc0 + 0]  = *(const float4*)(src + 0);
        *(float4*)&Vs[row][lc0 + 4]  = *(const float4*)(src + 4);
        *(float4*)&Vs[row][lc0 + 8]  = *(const float4*)(src + 8);
        *(float4*)&Vs[row][lc0 + 12] = *(const float4*)(src + 12);
    }
    for (int t = tid; t < 36 * 128; t += 256) {
        int u = t >> 7, kk = t & 127;
        Wt[u][kk] = (u < U_) ? Sbase[(size_t)u * 1024 + kk] : 0.f;
    }
    __syncthreads();

    float acc[9];
#pragma unroll
    for (int j = 0; j < 9; j++) acc[j] = 0.f;
#pragma unroll 2
    for (int kk = 0; kk < 128; ++kk) {
        float vv = Vs[kk][td];
#pragma unroll
        for (int j = 0; j < 9; j++) acc[j] = fmaf(Wt[tg + 4 * j][kk], vv, acc[j]);
    }
#pragma unroll
    for (int j = 0; j < 9; j++) {
        int u = tg + 4 * j;
        if (u < U_)
            ctxp[((size_t)(kc * 128 + bh) * 36 + u) * 64 + td] = acc[j];
    }
}

// ---------------------------------------------------------------
// ctxd[bh][u][d] = sum_kc ctxp - vmean[bh][d] ; grid 1120 x 256
// ---------------------------------------------------------------
__global__ __launch_bounds__(256) void ctx_reduce_diff(
    const float* __restrict__ ctxp, const float* __restrict__ vmean,
    float* __restrict__ ctxd)
{
    const int i = blockIdx.x * 256 + threadIdx.x;   // 128*35*64 = 286720
    const int d = i & 63;
    const int rest = i >> 6;
    const int u = rest % U_;
    const int bh = rest / U_;
    float s = 0.f;
#pragma unroll
    for (int kc = 0; kc < 8; ++kc)
        s += ctxp[((size_t)(kc * 128 + bh) * 36 + u) * 64 + d];
    ctxd[i] = s - vmean[(size_t)bh * 64 + d];
}

// ---------------------------------------------------------------
// obase[b][n] = dot(xbar[b], Wo[n]) + bo[n] ; grid 128 (16 b x 8 nchunk)
// ---------------------------------------------------------------
__global__ __launch_bounds__(256) void vmean_proj(
    const float* __restrict__ vmean, const float* __restrict__ Wo,
    const float* __restrict__ bo, float* __restrict__ obase)
{
    const int b = blockIdx.x >> 3, n0 = (blockIdx.x & 7) * 64;
    const int tid = threadIdx.x;
    __shared__ float xbar[512];
    __shared__ float psum[64][5];
    for (int i = tid; i < 512; i += 256)
        xbar[i] = vmean[(size_t)(b * 8 + (i >> 6)) * 64 + (i & 63)];
    __syncthreads();
    const int n = n0 + (tid >> 2), fq = (tid & 3) * 128;
    float s = 0.f;
    for (int f = 0; f < 128; f += 4) {
        float4 w = *(const float4*)(Wo + (size_t)n * 512 + fq + f);
        s += xbar[fq + f] * w.x + xbar[fq + f + 1] * w.y +
             xbar[fq + f + 2] * w.z + xbar[fq + f + 3] * w.w;
    }
    psum[tid >> 2][tid & 3] = s;
    __syncthreads();
    if (tid < 64)
        obase[(size_t)b * 512 + n0 + tid] =
            psum[tid][0] + psum[tid][1] + psum[tid][2] + psum[tid][3] + bo[n0 + tid];
}

// ---------------------------------------------------------------
// out[b][l][:] = obase[b][:] ; grid 8192 x 256 (float4)
// ---------------------------------------------------------------
__global__ void broadcast_out(const float* __restrict__ obase, float* __restrict__ out)
{
    const size_t e = ((size_t)blockIdx.x * 256 + threadIdx.x) * 4;
    const int n = (int)(e & 511);
    const int b = (int)(e >> 19);
    *(float4*)(out + e) = *(const float4*)(obase + (b << 9) + n);
}

// ---------------------------------------------------------------
// out[b][l_u][n] += ctxd[bh][u] . Wo[n][h*64..]
// grid (128 bh, 4 col-chunks) x 128 threads; one column n per thread.
// ---------------------------------------------------------------
__global__ __launch_bounds__(128) void delta_out(
    const float* __restrict__ ctxd, const int* __restrict__ idx,
    const float* __restrict__ Wo, float* __restrict__ out)
{
    const int bh = blockIdx.x, b = bh >> 3, h = bh & 7;
    const int tid = threadIdx.x;
    const int n = blockIdx.y * 128 + tid;
    __shared__ float sd[U_][64];
    __shared__ int ls[U_];
    if (tid < U_) ls[tid] = idx[bh * U_ + tid];
    for (int t = tid; t < U_ * 64; t += 128)
        sd[t >> 6][t & 63] = ctxd[(size_t)bh * U_ * 64 + t];

    float4 w[16];
    const float* wp = Wo + (size_t)n * 512 + h * 64;
#pragma unroll
    for (int jc = 0; jc < 16; ++jc) w[jc] = *(const float4*)(wp + jc * 4);
    __syncthreads();

    for (int u = 0; u < U_; ++u) {
        float acc = 0.f;
#pragma unroll
        for (int jc = 0; jc < 16; ++jc) {
            float4 dv = *(const float4*)&sd[u][jc * 4];
            acc = fmaf(dv.w, w[jc].w, fmaf(dv.z, w[jc].z,
                  fmaf(dv.y, w[jc].y, fmaf(dv.x, w[jc].x, acc))));
        }
        atomicAdd(out + ((size_t)b * L_ + ls[u]) * 512 + n, acc);
    }
}

// ---------------------------------------------------------------
extern "C" void kernel_launch(void* const* d_in, const int* in_sizes, int n_in,
                              void* d_out, int out_size, void* d_ws, size_t ws_size,
                              hipStream_t stream)
{
    (void)in_sizes; (void)n_in; (void)out_size; (void)ws_size;
    const float* query = (const float*)d_in[0];
    const float* key   = (const float*)d_in[1];
    const float* value = (const float*)d_in[2];
    const int*   mask  = (const int*)d_in[3];
    const float* Wq = (const float*)d_in[4];
    const float* bq = (const float*)d_in[5];
    const float* Wk = (const float*)d_in[6];
    const float* bk = (const float*)d_in[7];
    const float* Wv = (const float*)d_in[8];
    const float* bvp = (const float*)d_in[9];
    const float* Wo = (const float*)d_in[10];
    const float* bo = (const float*)d_in[11];
    float* out = (float*)d_out;

    float* ws = (float*)d_ws;
    float* v      = ws + OFF_V;
    unsigned short* q_hi = (unsigned short*)(ws + OFF_QHI);
    unsigned short* q_lo = (unsigned short*)(ws + OFF_QLO);
    unsigned short* k_hi = (unsigned short*)(ws + OFF_KHI);
    unsigned short* k_lo = (unsigned short*)(ws + OFF_KLO);
    float* ctxp   = ws + OFF_CTXP;
    float* S      = ws + OFF_S;
    float* Marr   = ws + OFF_M;
    float* kmean  = ws + OFF_KMEAN;
    float* vmean  = ws + OFF_VMEAN;
    float* ctxd   = ws + OFF_CTXD;
    int*   idx    = (int*)(ws + OFF_IDX);
    float* obase  = ws + OFF_OBASE;
    unsigned short* wqh = (unsigned short*)(ws + OFF_WQH);
    unsigned short* wql = (unsigned short*)(ws + OFF_WQL);
    unsigned short* wkh = (unsigned short*)(ws + OFF_WKH);
    unsigned short* wkl = (unsigned short*)(ws + OFF_WKL);
    unsigned short* wvh = (unsigned short*)(ws + OFF_WVH);
    unsigned short* wvl = (unsigned short*)(ws + OFF_WVL);

    // weight splits (fused)
    split_w3<<<3072, 256, 0, stream>>>(Wq, Wk, Wv, wqh, wql, wkh, wkl, wvh, wvl);

    // projections: fused dispatch, T14 async A-prefetch, swizzled B,
    // LDS-staged coalesced epilogue.
    gemm_qkv<<<dim3(128, 4, 3), 256, 0, stream>>>(
        query, key, value,
        wqh, wql, wkh, wkl, wvh, wvl,
        bq, bk, bvp,
        v, q_hi, q_lo, k_hi, k_lo);

    // per-(b,h) means (fused) + base output row
    means_fused<<<256, 256, 0, stream>>>(k_hi, k_lo, v, kmean, vmean);
    vmean_proj<<<128, 256, 0, stream>>>(vmean, Wo, bo, obase);

    // sparsity measure M (MFMA, XCD-local K, dbuf gload_lds, 1 barrier/tile)
    qk_rowmax_mfma<<<dim3(128, 16), 256, 0, stream>>>(q_hi, q_lo, k_hi, k_lo, kmean, Marr);
    topk35<<<128, 256, 0, stream>>>(Marr, idx);

    // reduced attention (K-split for parallelism)
    scores_red<<<dim3(128, 8), 256, 0, stream>>>(q_hi, q_lo, k_hi, k_lo, idx, mask, S);
    softmax_rows<<<B_ * H_ * U_, 256, 0, stream>>>(S);
    ctx_partial<<<dim3(128, 8), 256, 0, stream>>>(S, v, ctxp);   // ctxp aliases q_hi (dead)
    ctx_reduce_diff<<<1120, 256, 0, stream>>>(ctxp, vmean, ctxd);

    // output = broadcast base row + sparse delta (replaces full Wo GEMM)
    broadcast_out<<<8192, 256, 0, stream>>>(obase, out);
    delta_out<<<dim3(128, 4), 128, 0, stream>>>(ctxd, idx, Wo, out);
}